// Round 9
// baseline (232.936 us; speedup 1.0000x reference)
//
#include <hip/hip_runtime.h>
#include <hip/hip_bf16.h>
#include <math.h>

// MambaBlock: 4-direction 2D selective scan + fuse + LN + SiLU
// B=2, H=W=128, D_MODEL=64, D_INNER=128, D_STATE=16, DT_RANK=4, D_CONV=4
//
// R20 = chunked scan. R19 refuted the tail theory (2x512blk = 120us > 104us)
// and bounded k0,k3 < 60us each. Ladder: scan is serial-chain-bound; waves
// help (R15 512thr = 95us work-adj, best), instruction cuts don't (R13 null).
// First attack on the chain itself: fast path has e_j = E^(j+1), so a 2-chunk
// split has closed-form correction y_corr[l] = sum_j C_j G[l]^(j+1) h_in_j
// with SCALAR G[l] = prod E. Pass 1: chunks 0/1 scan 64 tokens in parallel
// (chunk1 from h=0, bf16 partials); h_end(c0) -> 8KB LDS; barrier; pass 2:
// chunk-1 threads add correction in 64 INDEPENDENT iters (recompute E, no
// log). Frame = R15's 512-thr (16 waves/CU, phases 2/3/4/6 verbatim).
// launch_bounds(512,4) caps VGPR 128 (protect 2 blk/CU). Fallback: full
// serial on chunk-0 (A_log = log(1..16) -> never taken).
//
//  K0: fold out_w*fuse_w -> MT16; in_w/xp_w -> bf16; x -> xhwc16 AND xwhc16.
//  K3 (67,584B LDS, 2 blk/CU, 512 thr): gather, MFMA vs MT16, LN, SiLU.

typedef __attribute__((ext_vector_type(8))) short short8;
typedef __attribute__((ext_vector_type(4))) float f32x4;
typedef __attribute__((ext_vector_type(2))) float f32x2;

__device__ __forceinline__ f32x2 pk_mul(f32x2 a, f32x2 b) {
  f32x2 d;
  asm("v_pk_mul_f32 %0, %1, %2" : "=v"(d) : "v"(a), "v"(b));
  return d;
}
__device__ __forceinline__ f32x2 pk_fma(f32x2 a, f32x2 b, f32x2 c) {
  f32x2 d;
  asm("v_pk_fma_f32 %0, %1, %2, %3" : "=v"(d) : "v"(a), "v"(b), "v"(c));
  return d;
}

__device__ __forceinline__ unsigned int pk2bf(float a, float b) {
  __hip_bfloat162 h = __float22bfloat162_rn(make_float2(a, b));
  unsigned int u;
  __builtin_memcpy(&u, &h, 4);
  return u;
}
__device__ __forceinline__ unsigned short f2bf(float f) {
  __hip_bfloat16 h = __float2bfloat16(f);
  unsigned short s;
  __builtin_memcpy(&s, &h, 2);
  return s;
}
__device__ __forceinline__ float bf2f(unsigned short h) {
  return __uint_as_float(((unsigned int)h) << 16);
}
__device__ __forceinline__ float fastrcp(float x) { return __builtin_amdgcn_rcpf(x); }
__device__ __forceinline__ float siluf(float x) { return x * fastrcp(1.f + __expf(-x)); }
__device__ __forceinline__ float dpp_swap1(float x) {
  return __uint_as_float((unsigned int)__builtin_amdgcn_mov_dpp(
           (int)__float_as_uint(x), 0xB1, 0xF, 0xF, true));
}

// ---------------------------------------------------------------- K0
// blk 0..127: fold -> MT16. 128..159: in_w -> W16. 160..163: xp_w -> XW16.
// blk 164..419: x[b][c][h][w] -> xhwc16[b][h][w][c] AND xwhc16[b][w][h][c].
__global__ void k0_prep(const float* __restrict__ out_w, const float* __restrict__ fuse_w,
                        const float* __restrict__ in_w, const float* __restrict__ xp_w,
                        const float* __restrict__ x,
                        unsigned short* __restrict__ MT16, unsigned short* __restrict__ W16,
                        unsigned short* __restrict__ XW16, unsigned short* __restrict__ XH,
                        unsigned short* __restrict__ XW) {
  __shared__ unsigned short sT[64*132];   // transpose stage (blk>=164 only)
  int blk = blockIdx.x;
  int tid = threadIdx.x;
  if (blk < 128) {
    int idx = blk * 256 + tid;   // 32768
    int d   = idx & 127;
    int o   = (idx >> 7) & 63;
    int dir = idx >> 13;
    float acc = 0.f;
    #pragma unroll 8
    for (int j = 0; j < 64; ++j)
      acc += out_w[(dir*64 + j)*128 + d] * fuse_w[o*256 + dir*64 + j];
    MT16[o*512 + dir*128 + d] = f2bf(acc);   // M^T layout [o][j=dir*128+d]
  } else if (blk < 160) {
    int t = (blk - 128) * 256 + tid;
    int base = t * 8;                        // 65536 total
    float4 v0 = *(const float4*)(in_w + base);
    float4 v1 = *(const float4*)(in_w + base + 4);
    uint4 pk;
    pk.x = pk2bf(v0.x, v0.y);
    pk.y = pk2bf(v0.z, v0.w);
    pk.z = pk2bf(v1.x, v1.y);
    pk.w = pk2bf(v1.z, v1.w);
    *(uint4*)(W16 + base) = pk;
  } else if (blk < 164) {
    int t = (blk - 160) * 256 + tid;        // 1024 threads
    for (int pid = t; pid < 4*48*128; pid += 1024) {
      int dir = pid / 6144;
      int rem = pid - dir*6144;
      int row = rem >> 7, c = rem & 127;
      XW16[pid] = (row < 36) ? f2bf(xp_w[dir*4608 + row*128 + c]) : (unsigned short)0;
    }
  } else {
    int idx = blk - 164;                    // 0..255
    int b = idx >> 7, h = idx & 127;
    for (int f = tid*4; f < 8192; f += 1024) {
      int c = f >> 7, w = f & 127;
      float4 v = *(const float4*)(x + (((size_t)(b*64 + c)*128 + h)*128 + w));
      sT[c*132 + w + 0] = f2bf(v.x);
      sT[c*132 + w + 1] = f2bf(v.y);
      sT[c*132 + w + 2] = f2bf(v.z);
      sT[c*132 + w + 3] = f2bf(v.w);
    }
    __syncthreads();
    for (int f = tid*8; f < 8192; f += 2048) {
      int w = f >> 6, c0 = f & 63;
      unsigned int pk[4];
      #pragma unroll
      for (int p = 0; p < 4; ++p) {
        unsigned int lo = sT[(c0 + p*2 + 0)*132 + w];
        unsigned int hi = sT[(c0 + p*2 + 1)*132 + w];
        pk[p] = lo | (hi << 16);
      }
      uint4 v; v.x = pk[0]; v.y = pk[1]; v.z = pk[2]; v.w = pk[3];
      *(uint4*)(XH + (((size_t)(b*128 + h)*128 + w)*64 + c0)) = v;
      *(uint4*)(XW + (((size_t)(b*128 + w)*128 + h)*64 + c0)) = v;
    }
  }
}

// ---------------------------------------------------------------- K1 (fused, 512 thr)
// LDS (61,440 B -> 2 blocks/CU with 512 thr, 16 waves/CU):
//   sBCf @0     18432B fp32 [128 tok][36] (B cols 0..15, C cols 16..31) [ph4+]
//   sUC  @18432 34816B bf16 [128 tok][136]; cols 0..127 = u_pre -> uc -> y;
//                      cols 128..135 = dt-rank float4 [ph4+]
//   hbuf @53248  8192B fp32 [128 ch][16 states]  (chunk-0 h_end handoff)
__global__ __launch_bounds__(512, 4) void k1_front(
    const unsigned short* __restrict__ XH, const unsigned short* __restrict__ XW,
    const unsigned short* __restrict__ W16, const unsigned short* __restrict__ XW16,
    const float* __restrict__ conv_w, const float* __restrict__ conv_b,
    const float* __restrict__ dtp_w, const float* __restrict__ dtp_b,
    const float* __restrict__ A_log, const float* __restrict__ Dp,
    unsigned short* __restrict__ YF)
{
  __shared__ __align__(16) char smem[61440];
  float* sBCf         = (float*)smem;                      // [128][36]  (ph4+)
  unsigned short* sUC = (unsigned short*)(smem + 18432);   // [128][136]
  float* hbuf         = (float*)(smem + 53248);            // [128][16]

  const int tid = threadIdx.x;
  const int dir = blockIdx.x >> 8;
  const int n   = blockIdx.x & 255;
  const int b   = n >> 7;
  const int r   = n & 127;
  const int n_all = dir*256 + n;

  const unsigned short* xsrc = (dir < 2 ? XH : XW) + ((size_t)(b*128 + r)*128)*64;

  const int wave = tid >> 6;          // 0..7: owns token group wave*16
  const int lane = tid & 63;
  const int m16 = lane & 15;
  const int quad = lane >> 4;
  const int st = wave*16 + m16;       // scan-order token owned in MFMA phases
  const int sp = (dir & 1) ? (127 - st) : st;   // spatial index in xsrc

  unsigned int zpk[8][2];   // silu(z) bf16-packed for token st: [k][pair]

  // ---- phase 2: MFMA in-projection. Each wave: its 16 tokens, 16 row-tiles. ----
  {
    short8 bfr[2];
    #pragma unroll
    for (int ks = 0; ks < 2; ++ks)
      bfr[ks] = *(const short8*)(xsrc + sp*64 + ks*32 + quad*8);
    const unsigned short* Wd = W16 + (size_t)dir * 16384;

    // u rows (rt 0..7)
    for (int rt = 0; rt < 8; ++rt) {
      short8 af[2];
      #pragma unroll
      for (int ks = 0; ks < 2; ++ks)
        af[ks] = *(const short8*)(Wd + (rt*16 + m16)*64 + ks*32 + quad*8);
      f32x4 acc = {0.f, 0.f, 0.f, 0.f};
      acc = __builtin_amdgcn_mfma_f32_16x16x32_bf16(af[0], bfr[0], acc, 0, 0, 0);
      acc = __builtin_amdgcn_mfma_f32_16x16x32_bf16(af[1], bfr[1], acc, 0, 0, 0);
      const int r0 = rt*16 + quad*4;
      uint2 u2;
      u2.x = pk2bf(acc[0], acc[1]);
      u2.y = pk2bf(acc[2], acc[3]);
      *(uint2*)(sUC + st*136 + r0) = u2;
    }
    // z rows (rt 8..15) -> registers
    #pragma unroll
    for (int k = 0; k < 8; ++k) {
      short8 af[2];
      #pragma unroll
      for (int ks = 0; ks < 2; ++ks)
        af[ks] = *(const short8*)(Wd + ((8+k)*16 + m16)*64 + ks*32 + quad*8);
      f32x4 acc = {0.f, 0.f, 0.f, 0.f};
      acc = __builtin_amdgcn_mfma_f32_16x16x32_bf16(af[0], bfr[0], acc, 0, 0, 0);
      acc = __builtin_amdgcn_mfma_f32_16x16x32_bf16(af[1], bfr[1], acc, 0, 0, 0);
      zpk[k][0] = pk2bf(siluf(acc[0]), siluf(acc[1]));
      zpk[k][1] = pk2bf(siluf(acc[2]), siluf(acc[3]));
    }
  }
  __syncthreads();

  // ---- phase 3: causal conv-4 + silu in sUC (bf16). 4 chunks of 32 tokens,
  //      fully parallel: thread (d = tid&127, chunk = tid>>7).
  {
    const int d = tid & 127;
    const int c4 = tid >> 7;           // chunk 0..3
    const int ca = c4 * 32;
    const float* cw = conv_w + (size_t)(dir*128 + d)*4;
    const float c0w = cw[0], c1w = cw[1], c2w = cw[2], c3w = cw[3];
    const float cbv = conv_b[dir*128 + d];
    float a0 = c4 ? bf2f(sUC[(ca-3)*136 + d]) : 0.f;
    float a1 = c4 ? bf2f(sUC[(ca-2)*136 + d]) : 0.f;
    float a2 = c4 ? bf2f(sUC[(ca-1)*136 + d]) : 0.f;
    __syncthreads();                   // all predecessor reads before any write
    unsigned short* pa = sUC + ca*136 + d;
    for (int i = 0; i < 32; ++i) {
      float cur = bf2f(*pa);
      float v = cbv + c0w*a0 + c1w*a1 + c2w*a2 + c3w*cur;
      *pa = f2bf(siluf(v));
      a0 = a1; a1 = a2; a2 = cur;
      pa += 136;
    }
  }
  __syncthreads();

  // ---- phase 4: MFMA xp-projection. Each wave: its 16 tokens, rt 0..2. ----
  {
    short8 bfr[4];
    #pragma unroll
    for (int ks = 0; ks < 4; ++ks)
      bfr[ks] = *(const short8*)(sUC + st*136 + ks*32 + quad*8);

    const unsigned short* XWd = XW16 + (size_t)dir * (48*128);

    for (int rt = 0; rt < 3; ++rt) {
      short8 af[4];
      #pragma unroll
      for (int ks = 0; ks < 4; ++ks)
        af[ks] = *(const short8*)(XWd + (rt*16 + m16)*128 + ks*32 + quad*8);
      f32x4 acc = {0.f, 0.f, 0.f, 0.f};
      #pragma unroll
      for (int ks = 0; ks < 4; ++ks)
        acc = __builtin_amdgcn_mfma_f32_16x16x32_bf16(af[ks], bfr[ks], acc, 0, 0, 0);
      const int r0 = rt*16 + quad*4;   // 0,4,...,44
      if (r0 == 0) {
        float4 v; v.x = acc[0]; v.y = acc[1]; v.z = acc[2]; v.w = acc[3];
        *(float4*)(smem + 18432 + st*272 + 256) = v;      // sUC cols 128..135
      } else if (r0 < 36) {
        float4 v; v.x = acc[0]; v.y = acc[1]; v.z = acc[2]; v.w = acc[3];
        *(float4*)(sBCf + st*36 + (r0 - 4)) = v;          // B: 0..15, C: 16..31
      }
    }
  }
  __syncthreads();

  // ---- phase 5: chunked selective scan. (ch, p) x chunk c; 2 thr/channel.
  //      Pass 1: both 64-token chunks in parallel (chunk 1 from h=0).
  //      Pass 2: chunk-1 correction y += C . G^(j+1) h_in (independent iters).
  {
    const int p = tid & 1;
    const int d = (tid >> 1) & 127;
    const int c = tid >> 8;           // chunk 0 / 1
    const float* dwp = dtp_w + (size_t)(dir*128 + d) * 4;
    const float dw0 = dwp[0], dw1 = dwp[1], dw2 = dwp[2], dw3 = dwp[3];
    const float db = dtp_b[dir*128 + d];
    const float dpv = Dp[dir*128 + d];

    float Av[8];
    bool fast = true;
    #pragma unroll
    for (int j = 0; j < 8; ++j) {
      float a = -__expf(A_log[((size_t)(dir*128 + d))*16 + p*8 + j]);
      Av[j] = a;
      if (fabsf((-a) - (float)(p*8 + j + 1)) > 1e-3f) fast = false;
    }

    if (fast) {
      // pass 1: local scan of this chunk's 64 tokens (chunk 1: h from 0)
      f32x2 h0 = {0.f, 0.f}, h1 = {0.f, 0.f}, h2v = {0.f, 0.f}, h3 = {0.f, 0.f};
      const char* qp = smem + 18432 + 256 + c*64*272;
      const float* bp = sBCf + c*64*36 + p*8;
      const float* cp = sBCf + c*64*36 + 16 + p*8;
      const unsigned short* up = sUC + c*64*136 + d;
      unsigned short* yo = sUC + c*64*136 + d;
      for (int l = 0; l < 64; ++l) {
        float4 Q = *(const float4*)qp;
        f32x2 B01 = *(const f32x2*)(bp + 0), B23 = *(const f32x2*)(bp + 2);
        f32x2 B45 = *(const f32x2*)(bp + 4), B67 = *(const f32x2*)(bp + 6);
        f32x2 C01 = *(const f32x2*)(cp + 0), C23 = *(const f32x2*)(cp + 2);
        f32x2 C45 = *(const f32x2*)(cp + 4), C67 = *(const f32x2*)(cp + 6);
        float u = bf2f(*up);
        float dr = Q.x*dw0 + Q.y*dw1 + Q.z*dw2 + Q.w*dw3 + db;
        float te = __expf(dr);
        float dt = (dr > 20.f) ? dr : __logf(1.f + te);
        float dtu = dt * u;
        float E = fastrcp(1.f + te);
        float E2 = E*E, E4 = E2*E2, E8 = E4*E4;
        float eb = p ? E8 : 1.f;
        f32x2 P0 = {E*eb, E2*eb};
        f32x2 E2v = {E2, E2};
        f32x2 P1 = pk_mul(P0, E2v);
        f32x2 P2 = pk_mul(P1, E2v);
        f32x2 P3 = pk_mul(P2, E2v);
        f32x2 du = {dtu, dtu};
        h0  = pk_fma(h0,  P0, pk_mul(du, B01));
        h1  = pk_fma(h1,  P1, pk_mul(du, B23));
        h2v = pk_fma(h2v, P2, pk_mul(du, B45));
        h3  = pk_fma(h3,  P3, pk_mul(du, B67));
        f32x2 ya = pk_mul(h0, C01);
        f32x2 yb = pk_mul(h1, C23);
        ya = pk_fma(h2v, C45, ya);
        yb = pk_fma(h3,  C67, yb);
        float ypar = (ya.x + ya.y) + (yb.x + yb.y);
        float ot = dpp_swap1(ypar);
        float ysum = ypar + ot;                  // bit-identical on both lanes
        *yo = f2bf(ysum + u*dpv);                // same value, same addr: benign
        qp += 272; bp += 36; cp += 36; up += 136; yo += 136;
      }
      if (c == 0) {                    // h_end handoff for chunk-1 correction
        float* hb = hbuf + d*16 + p*8;
        *(f32x2*)(hb + 0) = h0;
        *(f32x2*)(hb + 2) = h1;
        *(f32x2*)(hb + 4) = h2v;
        *(f32x2*)(hb + 6) = h3;
      }
    } else if (c == 0) {
      // general path: full serial 128 on chunk-0 threads (chunk-1 idle)
      float h[8];
      #pragma unroll
      for (int j = 0; j < 8; ++j) h[j] = 0.f;
      for (int l = 0; l < 128; ++l) {
        float4 Q = *(const float4*)(smem + 18432 + l*272 + 256);
        float4 b0 = *(const float4*)(sBCf + l*36 + p*8);
        float4 b1 = *(const float4*)(sBCf + l*36 + p*8 + 4);
        float4 c0 = *(const float4*)(sBCf + l*36 + 16 + p*8);
        float4 c1 = *(const float4*)(sBCf + l*36 + 16 + p*8 + 4);
        float Bv[8] = {b0.x,b0.y,b0.z,b0.w, b1.x,b1.y,b1.z,b1.w};
        float Cv[8] = {c0.x,c0.y,c0.z,c0.w, c1.x,c1.y,c1.z,c1.w};
        float u = bf2f(sUC[l*136 + d]);
        float dr = Q.x*dw0 + Q.y*dw1 + Q.z*dw2 + Q.w*dw3 + db;
        float te = __expf(dr);
        float dt = (dr > 20.f) ? dr : __logf(1.f + te);
        float dtu = dt * u;
        float yp = 0.f;
        #pragma unroll
        for (int j = 0; j < 8; ++j) {
          float ej = __expf(dt*Av[j]);
          h[j] = h[j]*ej + dtu*Bv[j];
          yp += h[j]*Cv[j];
        }
        float ot = dpp_swap1(yp);
        float ysum = yp + ot;
        if (p == 0) sUC[l*136 + d] = f2bf(ysum + u*dpv);
      }
    }
    __syncthreads();

    if (fast && c == 1) {
      // pass 2: correction. y[l] += sum_j C_j[l] G[l]^(j+1) h_in_j,
      // G[l] = prod_{k=64..l} E[k] (scalar). Iterations independent.
      const float* hb = hbuf + d*16 + p*8;
      f32x2 hin01 = *(const f32x2*)(hb + 0);
      f32x2 hin23 = *(const f32x2*)(hb + 2);
      f32x2 hin45 = *(const f32x2*)(hb + 4);
      f32x2 hin67 = *(const f32x2*)(hb + 6);
      float G = 1.f;
      const char* qp = smem + 18432 + 256 + 64*272;
      const float* cp = sBCf + 64*36 + 16 + p*8;
      unsigned short* yo = sUC + 64*136 + d;
      for (int l = 0; l < 64; ++l) {
        float4 Q = *(const float4*)qp;
        float dr = Q.x*dw0 + Q.y*dw1 + Q.z*dw2 + Q.w*dw3 + db;
        float te = __expf(dr);
        float E = fastrcp(1.f + te);
        G *= E;
        float G2 = G*G, G4 = G2*G2, G8 = G4*G4;
        float eb = p ? G8 : 1.f;
        f32x2 P0 = {G*eb, G2*eb};
        f32x2 G2v = {G2, G2};
        f32x2 P1 = pk_mul(P0, G2v);
        f32x2 P2 = pk_mul(P1, G2v);
        f32x2 P3 = pk_mul(P2, G2v);
        f32x2 C01 = *(const f32x2*)(cp + 0), C23 = *(const f32x2*)(cp + 2);
        f32x2 C45 = *(const f32x2*)(cp + 4), C67 = *(const f32x2*)(cp + 6);
        f32x2 a = pk_mul(pk_mul(P0, hin01), C01);
        a = pk_fma(pk_mul(P1, hin23), C23, a);
        a = pk_fma(pk_mul(P2, hin45), C45, a);
        a = pk_fma(pk_mul(P3, hin67), C67, a);
        float corr = a.x + a.y;
        float ot = dpp_swap1(corr);
        corr += ot;                              // full pair sum, both lanes
        *yo = f2bf(bf2f(*yo) + corr);            // benign dup write
        qp += 272; cp += 36; yo += 136;
      }
    }
  }
  __syncthreads();

  // ---- phase 6: yf = y * silu(z) from registers; dir-dependent YF layout. ----
  {
    size_t rowbase;
    if (dir < 2)       rowbase = ((size_t)n_all*128 + st)*128;
    else if (dir == 2) rowbase = ((size_t)(512 + b*128 + st)*128 + r)*128;
    else               rowbase = ((size_t)(768 + b*128 + (127-st))*128 + r)*128;
    #pragma unroll
    for (int k = 0; k < 8; ++k) {
      const int dz = 16*k + quad*4;
      uint2 yv = *(const uint2*)(sUC + st*136 + dz);
      float y0 = __uint_as_float(yv.x << 16);
      float y1 = __uint_as_float(yv.x & 0xffff0000u);
      float y2 = __uint_as_float(yv.y << 16);
      float y3 = __uint_as_float(yv.y & 0xffff0000u);
      unsigned int z01 = zpk[k][0], z23 = zpk[k][1];
      float z0 = __uint_as_float(z01 << 16);
      float z1 = __uint_as_float(z01 & 0xffff0000u);
      float z2 = __uint_as_float(z23 << 16);
      float z3 = __uint_as_float(z23 & 0xffff0000u);
      uint2 ov;
      ov.x = pk2bf(y0*z0, y1*z1);
      ov.y = pk2bf(y2*z2, y3*z3);
      *(uint2*)(YF + rowbase + dz) = ov;
    }
  }
}

// ---------------------------------------------------------------- K3 (MFMA fuse + LN)
// 512 threads, 2 blocks/CU -> 16 waves/CU. Grid 512 = 1 resident round.
__global__ __launch_bounds__(512, 2) void k3_fuse(
    const unsigned short* __restrict__ YF, const unsigned short* __restrict__ MT16,
    const float* __restrict__ fuse_b, const float* __restrict__ ln_g,
    const float* __restrict__ ln_b, float* __restrict__ out)
{
  __shared__ __align__(16) unsigned short sYB[64*520];   // 66,560 B
  __shared__ float sLN[2][64][2];                        //  1,024 B

  const int tid = threadIdx.x;
  const int blk = blockIdx.x;             // 512
  const int b = blk >> 8;
  const int rr2 = blk & 255;
  const int h = rr2 >> 1;
  const int w0 = (rr2 & 1) * 64;

  for (int f = tid*8; f < 32768; f += 4096) {
    int dirg = f >> 13;
    int rem = f & 8191;
    int tok = rem >> 7;
    int dd = rem & 127;
    int X = (dirg == 1) ? (127 - w0 - tok) : (w0 + tok);
    size_t base = ((size_t)(dirg*256 + b*128 + h)*128 + X)*128 + dd;
    *(uint4*)(sYB + tok*520 + dirg*128 + dd) = *(const uint4*)(YF + base);
  }
  __syncthreads();

  const int wave = tid >> 6;     // 0..7
  const int lane = tid & 63;
  const int m16 = lane & 15;
  const int quad = lane >> 4;
  const int tg   = wave & 3;     // token group
  const int mh   = wave >> 2;    // mt half: 0 -> mt{0,1}, 1 -> mt{2,3}
  const int tok  = tg*16 + m16;

  short8 bfr[16];
  #pragma unroll
  for (int jt = 0; jt < 16; ++jt)
    bfr[jt] = *(const short8*)(sYB + tok*520 + jt*32 + quad*8);

  float facc[2][4];
  #pragma unroll
  for (int mi = 0; mi < 2; ++mi) {
    const int mt = mh*2 + mi;
    f32x4 acc = {0.f, 0.f, 0.f, 0.f};
    #pragma unroll
    for (int jt = 0; jt < 16; ++jt) {
      short8 af = *(const short8*)(MT16 + (size_t)(mt*16 + m16)*512 + jt*32 + quad*8);
      acc = __builtin_amdgcn_mfma_f32_16x16x32_bf16(af, bfr[jt], acc, 0, 0, 0);
    }
    facc[mi][0] = acc[0]; facc[mi][1] = acc[1]; facc[mi][2] = acc[2]; facc[mi][3] = acc[3];
  }

  float fv[8];
  float s1 = 0.f, s2 = 0.f;
  #pragma unroll
  for (int mi = 0; mi < 2; ++mi)
    #pragma unroll
    for (int rr = 0; rr < 4; ++rr) {
      int o = (mh*2 + mi)*16 + quad*4 + rr;
      float v = facc[mi][rr] + fuse_b[o];
      fv[mi*4 + rr] = v;
      s1 += v; s2 += v*v;
    }
  s1 += __shfl_xor(s1, 16, 64); s1 += __shfl_xor(s1, 32, 64);
  s2 += __shfl_xor(s2, 16, 64); s2 += __shfl_xor(s2, 32, 64);
  if (lane < 16) {
    sLN[mh][tok][0] = s1;
    sLN[mh][tok][1] = s2;
  }
  __syncthreads();
  float t1 = s1 + sLN[1 - mh][tok][0];
  float t2 = s2 + sLN[1 - mh][tok][1];
  float mu = t1 * (1.f/64.f);
  float var = t2 * (1.f/64.f) - mu*mu;
  float rs = rsqrtf(var + 1e-5f);

  #pragma unroll
  for (int mi = 0; mi < 2; ++mi)
    #pragma unroll
    for (int rr = 0; rr < 4; ++rr) {
      int o = (mh*2 + mi)*16 + quad*4 + rr;
      float v = (fv[mi*4 + rr] - mu) * rs * ln_g[o] + ln_b[o];
      out[((size_t)(b*64 + o)*128 + h)*128 + (w0 + tok)] = siluf(v);
    }
}

// ---------------------------------------------------------------- host
extern "C" void kernel_launch(void* const* d_in, const int* in_sizes, int n_in,
                              void* d_out, int out_size, void* d_ws, size_t ws_size,
                              hipStream_t stream) {
  const float* x      = (const float*)d_in[0];
  const float* in_w   = (const float*)d_in[1];
  const float* conv_w = (const float*)d_in[2];
  const float* conv_b = (const float*)d_in[3];
  const float* xp_w   = (const float*)d_in[4];
  const float* dtp_w  = (const float*)d_in[5];
  const float* dtp_b  = (const float*)d_in[6];
  const float* A_log  = (const float*)d_in[7];
  const float* Dp     = (const float*)d_in[8];
  const float* out_w  = (const float*)d_in[9];
  const float* fuse_w = (const float*)d_in[10];
  const float* fuse_b = (const float*)d_in[11];
  const float* ln_g   = (const float*)d_in[12];
  const float* ln_b   = (const float*)d_in[13];
  float* out = (float*)d_out;

  // ws layout (BYTES):
  char* ws = (char*)d_ws;
  unsigned short* YF   = (unsigned short*)(ws);              // 33,554,432 (yf, dir-layouts)
  unsigned short* MT16 = (unsigned short*)(ws + 33554432);   //     65,536
  unsigned short* W16  = (unsigned short*)(ws + 33619968);   //    131,072
  unsigned short* XW16 = (unsigned short*)(ws + 33751040);   //     49,152
  unsigned short* XH   = (unsigned short*)(ws + 33800192);   //  4,194,304 (xhwc16)
  unsigned short* XWt  = (unsigned short*)(ws + 37994496);   //  4,194,304 (xwhc16)
  // total 42,188,800 B

  k0_prep<<<dim3(420), dim3(256), 0, stream>>>(out_w, fuse_w, in_w, xp_w, x,
                                               MT16, W16, XW16, XH, XWt);
  k1_front<<<dim3(1024), dim3(512), 0, stream>>>(XH, XWt, W16, XW16, conv_w, conv_b,
                                                 dtp_w, dtp_b, A_log, Dp, YF);
  k3_fuse<<<dim3(512), dim3(512), 0, stream>>>(YF, MT16, fuse_b, ln_g, ln_b, out);
}

// Round 10
// 228.985 us; speedup vs baseline: 1.0173x; 1.0173x over previous
//
#include <hip/hip_runtime.h>
#include <hip/hip_bf16.h>
#include <math.h>

// MambaBlock: 4-direction 2D selective scan + fuse + LN + SiLU
// B=2, H=W=128, D_MODEL=64, D_INNER=128, D_STATE=16, DT_RANK=4, D_CONV=4
//
// R21 = chunked scan in the 256-thread frame. R20 validated the closed-form
// chunk correction numerically (absmax unchanged) but mounted it on the
// 512-thr frame whose front phases cost ~30us extra (1 token-group/wave).
// Now: R13/R16 frame (104us, VGPR 84) with phase 5 replaced by:
//   pass A: thread (d,p) scans chunk0 (tok 0-63, exact) and chunk1 (tok
//     64-127, h from 0, partial y) INTERLEAVED -> two independent dependence
//     chains, 2x ILP on the latency-bound serial chain (R12's same-chain
//     prefetch was null; independent chains attack the stall directly).
//   pass B: correction y[l] += sum_j C_j G^(j+1) h_in_j, G = running prod E
//     (scalar). h_in = this thread's own chunk0 end state (registers!) ->
//     no LDS handoff, no barrier, no hbuf; LDS stays 53,248 -> 3 blk/CU.
// Spill watch: VGPR <= 128 ok (waves/SIMD halve above); FETCH/WRITE
// inflation => spill => revert.
//
//  K0: fold out_w*fuse_w -> MT16; in_w/xp_w -> bf16; x -> xhwc16 AND xwhc16.
//  K3 (67,584B LDS, 2 blk/CU, 512 thr): gather, MFMA vs MT16, LN, SiLU.

typedef __attribute__((ext_vector_type(8))) short short8;
typedef __attribute__((ext_vector_type(4))) float f32x4;
typedef __attribute__((ext_vector_type(2))) float f32x2;

__device__ __forceinline__ f32x2 pk_mul(f32x2 a, f32x2 b) {
  f32x2 d;
  asm("v_pk_mul_f32 %0, %1, %2" : "=v"(d) : "v"(a), "v"(b));
  return d;
}
__device__ __forceinline__ f32x2 pk_fma(f32x2 a, f32x2 b, f32x2 c) {
  f32x2 d;
  asm("v_pk_fma_f32 %0, %1, %2, %3" : "=v"(d) : "v"(a), "v"(b), "v"(c));
  return d;
}

__device__ __forceinline__ unsigned int pk2bf(float a, float b) {
  __hip_bfloat162 h = __float22bfloat162_rn(make_float2(a, b));
  unsigned int u;
  __builtin_memcpy(&u, &h, 4);
  return u;
}
__device__ __forceinline__ unsigned short f2bf(float f) {
  __hip_bfloat16 h = __float2bfloat16(f);
  unsigned short s;
  __builtin_memcpy(&s, &h, 2);
  return s;
}
__device__ __forceinline__ float bf2f(unsigned short h) {
  return __uint_as_float(((unsigned int)h) << 16);
}
__device__ __forceinline__ float fastrcp(float x) { return __builtin_amdgcn_rcpf(x); }
__device__ __forceinline__ float siluf(float x) { return x * fastrcp(1.f + __expf(-x)); }
__device__ __forceinline__ float dpp_swap1(float x) {
  return __uint_as_float((unsigned int)__builtin_amdgcn_mov_dpp(
           (int)__float_as_uint(x), 0xB1, 0xF, 0xF, true));
}

// ---------------------------------------------------------------- K0
// blk 0..127: fold -> MT16. 128..159: in_w -> W16. 160..163: xp_w -> XW16.
// blk 164..419: x[b][c][h][w] -> xhwc16[b][h][w][c] AND xwhc16[b][w][h][c].
__global__ void k0_prep(const float* __restrict__ out_w, const float* __restrict__ fuse_w,
                        const float* __restrict__ in_w, const float* __restrict__ xp_w,
                        const float* __restrict__ x,
                        unsigned short* __restrict__ MT16, unsigned short* __restrict__ W16,
                        unsigned short* __restrict__ XW16, unsigned short* __restrict__ XH,
                        unsigned short* __restrict__ XW) {
  __shared__ unsigned short sT[64*132];   // transpose stage (blk>=164 only)
  int blk = blockIdx.x;
  int tid = threadIdx.x;
  if (blk < 128) {
    int idx = blk * 256 + tid;   // 32768
    int d   = idx & 127;
    int o   = (idx >> 7) & 63;
    int dir = idx >> 13;
    float acc = 0.f;
    #pragma unroll 8
    for (int j = 0; j < 64; ++j)
      acc += out_w[(dir*64 + j)*128 + d] * fuse_w[o*256 + dir*64 + j];
    MT16[o*512 + dir*128 + d] = f2bf(acc);   // M^T layout [o][j=dir*128+d]
  } else if (blk < 160) {
    int t = (blk - 128) * 256 + tid;
    int base = t * 8;                        // 65536 total
    float4 v0 = *(const float4*)(in_w + base);
    float4 v1 = *(const float4*)(in_w + base + 4);
    uint4 pk;
    pk.x = pk2bf(v0.x, v0.y);
    pk.y = pk2bf(v0.z, v0.w);
    pk.z = pk2bf(v1.x, v1.y);
    pk.w = pk2bf(v1.z, v1.w);
    *(uint4*)(W16 + base) = pk;
  } else if (blk < 164) {
    int t = (blk - 160) * 256 + tid;        // 1024 threads
    for (int pid = t; pid < 4*48*128; pid += 1024) {
      int dir = pid / 6144;
      int rem = pid - dir*6144;
      int row = rem >> 7, c = rem & 127;
      XW16[pid] = (row < 36) ? f2bf(xp_w[dir*4608 + row*128 + c]) : (unsigned short)0;
    }
  } else {
    int idx = blk - 164;                    // 0..255
    int b = idx >> 7, h = idx & 127;
    for (int f = tid*4; f < 8192; f += 1024) {
      int c = f >> 7, w = f & 127;
      float4 v = *(const float4*)(x + (((size_t)(b*64 + c)*128 + h)*128 + w));
      sT[c*132 + w + 0] = f2bf(v.x);
      sT[c*132 + w + 1] = f2bf(v.y);
      sT[c*132 + w + 2] = f2bf(v.z);
      sT[c*132 + w + 3] = f2bf(v.w);
    }
    __syncthreads();
    for (int f = tid*8; f < 8192; f += 2048) {
      int w = f >> 6, c0 = f & 63;
      unsigned int pk[4];
      #pragma unroll
      for (int p = 0; p < 4; ++p) {
        unsigned int lo = sT[(c0 + p*2 + 0)*132 + w];
        unsigned int hi = sT[(c0 + p*2 + 1)*132 + w];
        pk[p] = lo | (hi << 16);
      }
      uint4 v; v.x = pk[0]; v.y = pk[1]; v.z = pk[2]; v.w = pk[3];
      *(uint4*)(XH + (((size_t)(b*128 + h)*128 + w)*64 + c0)) = v;
      *(uint4*)(XW + (((size_t)(b*128 + w)*128 + h)*64 + c0)) = v;
    }
  }
}

// ---------------------------------------------------------------- K1 (fused)
// LDS (53,248 B -> 3 blocks/CU):
//   sBCf @0     18432B fp32 [128 tok][36] (B cols 0..15, C cols 16..31) [ph4+]
//   sUC  @18432 34816B bf16 [128 tok][136]; cols 0..127 = u_pre -> uc -> y;
//                      cols 128..135 = dt-rank float4 [ph4+]
__global__ __launch_bounds__(256, 3) void k1_front(
    const unsigned short* __restrict__ XH, const unsigned short* __restrict__ XW,
    const unsigned short* __restrict__ W16, const unsigned short* __restrict__ XW16,
    const float* __restrict__ conv_w, const float* __restrict__ conv_b,
    const float* __restrict__ dtp_w, const float* __restrict__ dtp_b,
    const float* __restrict__ A_log, const float* __restrict__ Dp,
    unsigned short* __restrict__ YF)
{
  __shared__ __align__(16) char smem[53248];
  float* sBCf         = (float*)smem;                      // [128][36]  (ph4+)
  unsigned short* sUC = (unsigned short*)(smem + 18432);   // [128][136]

  const int tid = threadIdx.x;
  const int dir = blockIdx.x >> 8;
  const int n   = blockIdx.x & 255;
  const int b   = n >> 7;
  const int r   = n & 127;
  const int n_all = dir*256 + n;

  const unsigned short* xsrc = (dir < 2 ? XH : XW) + ((size_t)(b*128 + r)*128)*64;

  const int wave = tid >> 6;
  const int lane = tid & 63;
  const int m16 = lane & 15;
  const int quad = lane >> 4;
  const int tb0 = wave * 32;
  const int st0 = tb0 + m16;          // scan-order tokens owned (B-fragment rows)
  const int st1 = tb0 + 16 + m16;
  const int sp0 = (dir & 1) ? (127 - st0) : st0;   // spatial index in xsrc
  const int sp1 = (dir & 1) ? (127 - st1) : st1;

  unsigned int zpk[2][8][2];   // silu(z) bf16-packed: [tok-half][k][pair] (32 VGPRs)

  // ---- phase 2: MFMA in-projection. A=in_w (global bf16), B=x (global bf16). ----
  {
    short8 bfr[2][2];
    #pragma unroll
    for (int ks = 0; ks < 2; ++ks) {
      bfr[0][ks] = *(const short8*)(xsrc + sp0*64 + ks*32 + quad*8);
      bfr[1][ks] = *(const short8*)(xsrc + sp1*64 + ks*32 + quad*8);
    }
    const unsigned short* Wd = W16 + (size_t)dir * 16384;

    // u rows (rt 0..7)
    for (int rt = 0; rt < 8; ++rt) {
      short8 af[2];
      #pragma unroll
      for (int ks = 0; ks < 2; ++ks)
        af[ks] = *(const short8*)(Wd + (rt*16 + m16)*64 + ks*32 + quad*8);
      #pragma unroll
      for (int tt = 0; tt < 2; ++tt) {
        f32x4 acc = {0.f, 0.f, 0.f, 0.f};
        acc = __builtin_amdgcn_mfma_f32_16x16x32_bf16(af[0], bfr[tt][0], acc, 0, 0, 0);
        acc = __builtin_amdgcn_mfma_f32_16x16x32_bf16(af[1], bfr[tt][1], acc, 0, 0, 0);
        const int tok = tt ? st1 : st0;
        const int r0 = rt*16 + quad*4;
        uint2 u2;
        u2.x = pk2bf(acc[0], acc[1]);
        u2.y = pk2bf(acc[2], acc[3]);
        *(uint2*)(sUC + tok*136 + r0) = u2;
      }
    }
    // z rows (rt 8..15) -> registers
    #pragma unroll
    for (int k = 0; k < 8; ++k) {
      short8 af[2];
      #pragma unroll
      for (int ks = 0; ks < 2; ++ks)
        af[ks] = *(const short8*)(Wd + ((8+k)*16 + m16)*64 + ks*32 + quad*8);
      #pragma unroll
      for (int tt = 0; tt < 2; ++tt) {
        f32x4 acc = {0.f, 0.f, 0.f, 0.f};
        acc = __builtin_amdgcn_mfma_f32_16x16x32_bf16(af[0], bfr[tt][0], acc, 0, 0, 0);
        acc = __builtin_amdgcn_mfma_f32_16x16x32_bf16(af[1], bfr[tt][1], acc, 0, 0, 0);
        zpk[tt][k][0] = pk2bf(siluf(acc[0]), siluf(acc[1]));
        zpk[tt][k][1] = pk2bf(siluf(acc[2]), siluf(acc[3]));
      }
    }
  }
  __syncthreads();

  // ---- phase 3: causal conv-4 + silu in sUC (bf16), packed 2-chunk. ----
  {
    const int d = tid & 127;
    const int half = tid >> 7;
    const int ca = half * 32;          // chunk A: 0 or 32
    const int cb2 = (half + 2) * 32;   // chunk B: 64 or 96
    const float* cw = conv_w + (size_t)(dir*128 + d)*4;
    const float c0w = cw[0], c1w = cw[1], c2w = cw[2], c3w = cw[3];
    const float cbv = conv_b[dir*128 + d];
    const f32x2 cw0v = {c0w, c0w}, cw1v = {c1w, c1w}, cw2v = {c2w, c2w}, cw3v = {c3w, c3w};
    const f32x2 cbv2 = {cbv, cbv};
    f32x2 A0 = { half ? bf2f(sUC[(ca-3)*136 + d]) : 0.f, bf2f(sUC[(cb2-3)*136 + d]) };
    f32x2 A1 = { half ? bf2f(sUC[(ca-2)*136 + d]) : 0.f, bf2f(sUC[(cb2-2)*136 + d]) };
    f32x2 A2 = { half ? bf2f(sUC[(ca-1)*136 + d]) : 0.f, bf2f(sUC[(cb2-1)*136 + d]) };
    __syncthreads();
    unsigned short* pa = sUC + ca*136 + d;
    unsigned short* pb = sUC + cb2*136 + d;
    for (int i = 0; i < 32; ++i) {
      f32x2 cur = { bf2f(*pa), bf2f(*pb) };
      f32x2 v = pk_fma(cw3v, cur,
                pk_fma(cw2v, A2,
                pk_fma(cw1v, A1,
                pk_fma(cw0v, A0, cbv2))));
      *pa = f2bf(siluf(v.x));
      *pb = f2bf(siluf(v.y));
      A0 = A1; A1 = A2; A2 = cur;
      pa += 136; pb += 136;
    }
  }
  __syncthreads();

  // ---- phase 4: MFMA xp-projection. A=xp_w (global bf16), B=uc (LDS sUC). ----
  {
    short8 bfr[2][4];
    #pragma unroll
    for (int tt = 0; tt < 2; ++tt)
      #pragma unroll
      for (int ks = 0; ks < 4; ++ks)
        bfr[tt][ks] = *(const short8*)(sUC + (tt ? st1 : st0)*136 + ks*32 + quad*8);

    const unsigned short* XWd = XW16 + (size_t)dir * (48*128);

    for (int rt = 0; rt < 3; ++rt) {
      short8 af[4];
      #pragma unroll
      for (int ks = 0; ks < 4; ++ks)
        af[ks] = *(const short8*)(XWd + (rt*16 + m16)*128 + ks*32 + quad*8);
      #pragma unroll
      for (int tt = 0; tt < 2; ++tt) {
        f32x4 acc = {0.f, 0.f, 0.f, 0.f};
        #pragma unroll
        for (int ks = 0; ks < 4; ++ks)
          acc = __builtin_amdgcn_mfma_f32_16x16x32_bf16(af[ks], bfr[tt][ks], acc, 0, 0, 0);
        const int tok = tt ? st1 : st0;
        const int r0 = rt*16 + quad*4;   // 0,4,...,44
        if (r0 == 0) {
          float4 v; v.x = acc[0]; v.y = acc[1]; v.z = acc[2]; v.w = acc[3];
          *(float4*)(smem + 18432 + tok*272 + 256) = v;      // sUC cols 128..135
        } else if (r0 < 36) {
          float4 v; v.x = acc[0]; v.y = acc[1]; v.z = acc[2]; v.w = acc[3];
          *(float4*)(sBCf + tok*36 + (r0 - 4)) = v;          // B: 0..15, C: 16..31
        }
      }
    }
  }
  __syncthreads();

  // ---- phase 5: dual-chunk interleaved scan + thread-local correction. ----
  //      pass A: chunk0 (exact) + chunk1 (h from 0) as 2 independent chains.
  //      pass B: y[64+i] += sum_j C_j G^(j+1) h_in_j; h_in in own registers.
  {
    const int d = tid >> 1;
    const int p = tid & 1;
    const float* dwp = dtp_w + (size_t)(dir*128 + d) * 4;
    const float dw0 = dwp[0], dw1 = dwp[1], dw2 = dwp[2], dw3 = dwp[3];
    const float db = dtp_b[dir*128 + d];
    const float dpv = Dp[dir*128 + d];

    float Av[8];
    bool fast = true;
    #pragma unroll
    for (int j = 0; j < 8; ++j) {
      float a = -__expf(A_log[((size_t)(dir*128 + d))*16 + p*8 + j]);
      Av[j] = a;
      if (fabsf((-a) - (float)(p*8 + j + 1)) > 1e-3f) fast = false;
    }

    if (fast) {
      // pass A
      f32x2 ha0 = {0.f,0.f}, ha1 = {0.f,0.f}, ha2 = {0.f,0.f}, ha3 = {0.f,0.f};
      f32x2 hb0 = {0.f,0.f}, hb1 = {0.f,0.f}, hb2 = {0.f,0.f}, hb3 = {0.f,0.f};
      const char* qpA = smem + 18432 + 256;
      const char* qpB = qpA + 64*272;
      const float* bpA = sBCf + p*8;
      const float* bpB = sBCf + 64*36 + p*8;
      const float* cpA = sBCf + 16 + p*8;
      const float* cpB = sBCf + 64*36 + 16 + p*8;
      const unsigned short* upA = sUC + d;
      const unsigned short* upB = sUC + 64*136 + d;
      unsigned short* yoA = sUC + d;
      unsigned short* yoB = sUC + 64*136 + d;
      for (int i = 0; i < 64; ++i) {
        float4 QA = *(const float4*)qpA;
        float4 QB = *(const float4*)qpB;
        float uA = bf2f(*upA);
        float uB = bf2f(*upB);
        f32x2 BA01 = *(const f32x2*)(bpA+0), BA23 = *(const f32x2*)(bpA+2);
        f32x2 BA45 = *(const f32x2*)(bpA+4), BA67 = *(const f32x2*)(bpA+6);
        f32x2 BB01 = *(const f32x2*)(bpB+0), BB23 = *(const f32x2*)(bpB+2);
        f32x2 BB45 = *(const f32x2*)(bpB+4), BB67 = *(const f32x2*)(bpB+6);
        f32x2 CA01 = *(const f32x2*)(cpA+0), CA23 = *(const f32x2*)(cpA+2);
        f32x2 CA45 = *(const f32x2*)(cpA+4), CA67 = *(const f32x2*)(cpA+6);
        f32x2 CB01 = *(const f32x2*)(cpB+0), CB23 = *(const f32x2*)(cpB+2);
        f32x2 CB45 = *(const f32x2*)(cpB+4), CB67 = *(const f32x2*)(cpB+6);
        float drA = QA.x*dw0 + QA.y*dw1 + QA.z*dw2 + QA.w*dw3 + db;
        float drB = QB.x*dw0 + QB.y*dw1 + QB.z*dw2 + QB.w*dw3 + db;
        float teA = __expf(drA), teB = __expf(drB);
        float dtA = (drA > 20.f) ? drA : __logf(1.f + teA);
        float dtB = (drB > 20.f) ? drB : __logf(1.f + teB);
        float duA = dtA * uA, duB = dtB * uB;
        float EA = fastrcp(1.f + teA), EB = fastrcp(1.f + teB);
        float EA2 = EA*EA, EA4 = EA2*EA2, EA8 = EA4*EA4;
        float EB2 = EB*EB, EB4 = EB2*EB2, EB8 = EB4*EB4;
        float ebA = p ? EA8 : 1.f;
        float ebB = p ? EB8 : 1.f;
        f32x2 PA0 = {EA*ebA, EA2*ebA};
        f32x2 EA2v = {EA2, EA2};
        f32x2 PA1 = pk_mul(PA0, EA2v);
        f32x2 PA2 = pk_mul(PA1, EA2v);
        f32x2 PA3 = pk_mul(PA2, EA2v);
        f32x2 PB0 = {EB*ebB, EB2*ebB};
        f32x2 EB2v = {EB2, EB2};
        f32x2 PB1 = pk_mul(PB0, EB2v);
        f32x2 PB2 = pk_mul(PB1, EB2v);
        f32x2 PB3 = pk_mul(PB2, EB2v);
        f32x2 duAv = {duA, duA}, duBv = {duB, duB};
        ha0 = pk_fma(ha0, PA0, pk_mul(duAv, BA01));
        ha1 = pk_fma(ha1, PA1, pk_mul(duAv, BA23));
        ha2 = pk_fma(ha2, PA2, pk_mul(duAv, BA45));
        ha3 = pk_fma(ha3, PA3, pk_mul(duAv, BA67));
        hb0 = pk_fma(hb0, PB0, pk_mul(duBv, BB01));
        hb1 = pk_fma(hb1, PB1, pk_mul(duBv, BB23));
        hb2 = pk_fma(hb2, PB2, pk_mul(duBv, BB45));
        hb3 = pk_fma(hb3, PB3, pk_mul(duBv, BB67));
        f32x2 ya = pk_mul(ha0, CA01);
        f32x2 yb = pk_mul(ha1, CA23);
        ya = pk_fma(ha2, CA45, ya);
        yb = pk_fma(ha3, CA67, yb);
        float yA = (ya.x + ya.y) + (yb.x + yb.y);
        f32x2 za = pk_mul(hb0, CB01);
        f32x2 zb = pk_mul(hb1, CB23);
        za = pk_fma(hb2, CB45, za);
        zb = pk_fma(hb3, CB67, zb);
        float yB = (za.x + za.y) + (zb.x + zb.y);
        float sA = yA + dpp_swap1(yA);
        float sB = yB + dpp_swap1(yB);
        *yoA = f2bf(sA + uA*dpv);                // exact
        *yoB = f2bf(sB + uB*dpv);                // partial, corrected in pass B
        qpA += 272; qpB += 272; bpA += 36; bpB += 36; cpA += 36; cpB += 36;
        upA += 136; upB += 136; yoA += 136; yoB += 136;
      }
      // pass B: independent iterations; h_in = ha0..ha3 (own registers).
      float G = 1.f;
      const char* qp = smem + 18432 + 256 + 64*272;
      const float* cp = sBCf + 64*36 + 16 + p*8;
      unsigned short* yo = sUC + 64*136 + d;
      for (int i = 0; i < 64; ++i) {
        float4 Q = *(const float4*)qp;
        float dr = Q.x*dw0 + Q.y*dw1 + Q.z*dw2 + Q.w*dw3 + db;
        float te = __expf(dr);
        float E = fastrcp(1.f + te);
        G *= E;
        float G2 = G*G, G4 = G2*G2, G8 = G4*G4;
        float eb = p ? G8 : 1.f;
        f32x2 P0 = {G*eb, G2*eb};
        f32x2 G2v = {G2, G2};
        f32x2 P1 = pk_mul(P0, G2v);
        f32x2 P2 = pk_mul(P1, G2v);
        f32x2 P3 = pk_mul(P2, G2v);
        f32x2 C01 = *(const f32x2*)(cp+0), C23 = *(const f32x2*)(cp+2);
        f32x2 C45 = *(const f32x2*)(cp+4), C67 = *(const f32x2*)(cp+6);
        f32x2 a = pk_mul(pk_mul(P0, ha0), C01);
        a = pk_fma(pk_mul(P1, ha1), C23, a);
        a = pk_fma(pk_mul(P2, ha2), C45, a);
        a = pk_fma(pk_mul(P3, ha3), C67, a);
        float corr = a.x + a.y;
        corr += dpp_swap1(corr);
        *yo = f2bf(bf2f(*yo) + corr);            // same value both pair lanes
        qp += 272; cp += 36; yo += 136;
      }
    } else {
      float h[8];
      #pragma unroll
      for (int j = 0; j < 8; ++j) h[j] = 0.f;
      for (int l = 0; l < 128; ++l) {
        float4 Q = *(const float4*)(smem + 18432 + l*272 + 256);
        float4 b0 = *(const float4*)(sBCf + l*36 + p*8);
        float4 b1 = *(const float4*)(sBCf + l*36 + p*8 + 4);
        float4 c0 = *(const float4*)(sBCf + l*36 + 16 + p*8);
        float4 c1 = *(const float4*)(sBCf + l*36 + 16 + p*8 + 4);
        float Bv[8] = {b0.x,b0.y,b0.z,b0.w, b1.x,b1.y,b1.z,b1.w};
        float Cv[8] = {c0.x,c0.y,c0.z,c0.w, c1.x,c1.y,c1.z,c1.w};
        float u = bf2f(sUC[l*136 + d]);
        float dr = Q.x*dw0 + Q.y*dw1 + Q.z*dw2 + Q.w*dw3 + db;
        float te = __expf(dr);
        float dt = (dr > 20.f) ? dr : __logf(1.f + te);
        float dtu = dt * u;
        float yp = 0.f;
        #pragma unroll
        for (int j = 0; j < 8; ++j) {
          float ej = __expf(dt*Av[j]);
          h[j] = h[j]*ej + dtu*Bv[j];
          yp += h[j]*Cv[j];
        }
        float ot = dpp_swap1(yp);
        float ysum = yp + ot;
        if (p == 0) sUC[l*136 + d] = f2bf(ysum + u*dpv);
      }
    }
  }
  __syncthreads();

  // ---- phase 6: yf = y * silu(z) from registers; dir-dependent YF layout. ----
  #pragma unroll
  for (int tt = 0; tt < 2; ++tt) {
    const int st = tt ? st1 : st0;
    size_t rowbase;
    if (dir < 2)       rowbase = ((size_t)n_all*128 + st)*128;
    else if (dir == 2) rowbase = ((size_t)(512 + b*128 + st)*128 + r)*128;
    else               rowbase = ((size_t)(768 + b*128 + (127-st))*128 + r)*128;
    #pragma unroll
    for (int k = 0; k < 8; ++k) {
      const int dz = 16*k + quad*4;
      uint2 yv = *(const uint2*)(sUC + st*136 + dz);
      float y0 = __uint_as_float(yv.x << 16);
      float y1 = __uint_as_float(yv.x & 0xffff0000u);
      float y2 = __uint_as_float(yv.y << 16);
      float y3 = __uint_as_float(yv.y & 0xffff0000u);
      unsigned int z01 = zpk[tt][k][0], z23 = zpk[tt][k][1];
      float z0 = __uint_as_float(z01 << 16);
      float z1 = __uint_as_float(z01 & 0xffff0000u);
      float z2 = __uint_as_float(z23 << 16);
      float z3 = __uint_as_float(z23 & 0xffff0000u);
      uint2 ov;
      ov.x = pk2bf(y0*z0, y1*z1);
      ov.y = pk2bf(y2*z2, y3*z3);
      *(uint2*)(YF + rowbase + dz) = ov;
    }
  }
}

// ---------------------------------------------------------------- K3 (MFMA fuse + LN)
// 512 threads, 2 blocks/CU -> 16 waves/CU. Grid 512 = 1 resident round.
__global__ __launch_bounds__(512, 2) void k3_fuse(
    const unsigned short* __restrict__ YF, const unsigned short* __restrict__ MT16,
    const float* __restrict__ fuse_b, const float* __restrict__ ln_g,
    const float* __restrict__ ln_b, float* __restrict__ out)
{
  __shared__ __align__(16) unsigned short sYB[64*520];   // 66,560 B
  __shared__ float sLN[2][64][2];                        //  1,024 B

  const int tid = threadIdx.x;
  const int blk = blockIdx.x;             // 512
  const int b = blk >> 8;
  const int rr2 = blk & 255;
  const int h = rr2 >> 1;
  const int w0 = (rr2 & 1) * 64;

  for (int f = tid*8; f < 32768; f += 4096) {
    int dirg = f >> 13;
    int rem = f & 8191;
    int tok = rem >> 7;
    int dd = rem & 127;
    int X = (dirg == 1) ? (127 - w0 - tok) : (w0 + tok);
    size_t base = ((size_t)(dirg*256 + b*128 + h)*128 + X)*128 + dd;
    *(uint4*)(sYB + tok*520 + dirg*128 + dd) = *(const uint4*)(YF + base);
  }
  __syncthreads();

  const int wave = tid >> 6;     // 0..7
  const int lane = tid & 63;
  const int m16 = lane & 15;
  const int quad = lane >> 4;
  const int tg   = wave & 3;     // token group
  const int mh   = wave >> 2;    // mt half: 0 -> mt{0,1}, 1 -> mt{2,3}
  const int tok  = tg*16 + m16;

  short8 bfr[16];
  #pragma unroll
  for (int jt = 0; jt < 16; ++jt)
    bfr[jt] = *(const short8*)(sYB + tok*520 + jt*32 + quad*8);

  float facc[2][4];
  #pragma unroll
  for (int mi = 0; mi < 2; ++mi) {
    const int mt = mh*2 + mi;
    f32x4 acc = {0.f, 0.f, 0.f, 0.f};
    #pragma unroll
    for (int jt = 0; jt < 16; ++jt) {
      short8 af = *(const short8*)(MT16 + (size_t)(mt*16 + m16)*512 + jt*32 + quad*8);
      acc = __builtin_amdgcn_mfma_f32_16x16x32_bf16(af, bfr[jt], acc, 0, 0, 0);
    }
    facc[mi][0] = acc[0]; facc[mi][1] = acc[1]; facc[mi][2] = acc[2]; facc[mi][3] = acc[3];
  }

  float fv[8];
  float s1 = 0.f, s2 = 0.f;
  #pragma unroll
  for (int mi = 0; mi < 2; ++mi)
    #pragma unroll
    for (int rr = 0; rr < 4; ++rr) {
      int o = (mh*2 + mi)*16 + quad*4 + rr;
      float v = facc[mi][rr] + fuse_b[o];
      fv[mi*4 + rr] = v;
      s1 += v; s2 += v*v;
    }
  s1 += __shfl_xor(s1, 16, 64); s1 += __shfl_xor(s1, 32, 64);
  s2 += __shfl_xor(s2, 16, 64); s2 += __shfl_xor(s2, 32, 64);
  if (lane < 16) {
    sLN[mh][tok][0] = s1;
    sLN[mh][tok][1] = s2;
  }
  __syncthreads();
  float t1 = s1 + sLN[1 - mh][tok][0];
  float t2 = s2 + sLN[1 - mh][tok][1];
  float mu = t1 * (1.f/64.f);
  float var = t2 * (1.f/64.f) - mu*mu;
  float rs = rsqrtf(var + 1e-5f);

  #pragma unroll
  for (int mi = 0; mi < 2; ++mi)
    #pragma unroll
    for (int rr = 0; rr < 4; ++rr) {
      int o = (mh*2 + mi)*16 + quad*4 + rr;
      float v = (fv[mi*4 + rr] - mu) * rs * ln_g[o] + ln_b[o];
      out[((size_t)(b*64 + o)*128 + h)*128 + (w0 + tok)] = siluf(v);
    }
}

// ---------------------------------------------------------------- host
extern "C" void kernel_launch(void* const* d_in, const int* in_sizes, int n_in,
                              void* d_out, int out_size, void* d_ws, size_t ws_size,
                              hipStream_t stream) {
  const float* x      = (const float*)d_in[0];
  const float* in_w   = (const float*)d_in[1];
  const float* conv_w = (const float*)d_in[2];
  const float* conv_b = (const float*)d_in[3];
  const float* xp_w   = (const float*)d_in[4];
  const float* dtp_w  = (const float*)d_in[5];
  const float* dtp_b  = (const float*)d_in[6];
  const float* A_log  = (const float*)d_in[7];
  const float* Dp     = (const float*)d_in[8];
  const float* out_w  = (const float*)d_in[9];
  const float* fuse_w = (const float*)d_in[10];
  const float* fuse_b = (const float*)d_in[11];
  const float* ln_g   = (const float*)d_in[12];
  const float* ln_b   = (const float*)d_in[13];
  float* out = (float*)d_out;

  // ws layout (BYTES):
  char* ws = (char*)d_ws;
  unsigned short* YF   = (unsigned short*)(ws);              // 33,554,432 (yf, dir-layouts)
  unsigned short* MT16 = (unsigned short*)(ws + 33554432);   //     65,536
  unsigned short* W16  = (unsigned short*)(ws + 33619968);   //    131,072
  unsigned short* XW16 = (unsigned short*)(ws + 33751040);   //     49,152
  unsigned short* XH   = (unsigned short*)(ws + 33800192);   //  4,194,304 (xhwc16)
  unsigned short* XWt  = (unsigned short*)(ws + 37994496);   //  4,194,304 (xwhc16)
  // total 42,188,800 B

  k0_prep<<<dim3(420), dim3(256), 0, stream>>>(out_w, fuse_w, in_w, xp_w, x,
                                               MT16, W16, XW16, XH, XWt);
  k1_front<<<dim3(1024), dim3(256), 0, stream>>>(XH, XWt, W16, XW16, conv_w, conv_b,
                                                 dtp_w, dtp_b, A_log, Dp, YF);
  k3_fuse<<<dim3(512), dim3(512), 0, stream>>>(YF, MT16, fuse_b, ln_g, ln_b, out);
}

// Round 11
// 205.403 us; speedup vs baseline: 1.1340x; 1.1148x over previous
//
#include <hip/hip_runtime.h>
#include <hip/hip_bf16.h>
#include <math.h>

// MambaBlock: 4-direction 2D selective scan + fuse + LN + SiLU
// B=2, H=W=128, D_MODEL=64, D_INNER=128, D_STATE=16, DT_RANK=4, D_CONV=4
//
// R22 = R16 revert (best: 203.5us total, k1 104us) + ONE variable: XCD-aware
// block swizzle on k1. R21's chunked scan spilled (FETCH 5->9MB, WRITE
// 33->44MB); scan body is at its source-level floor -- frozen at R13/R16.
// Swizzle: swz = (bid&7)*128 + bid>>3 (bijective, 1024%8==0). Each XCD gets
// a contiguous 128-block range = one (dir,b) slice -> its XH/XW reads fit
// the 2MB window in 4MB XCD-L2, weights single-dir hot. Correctness-neutral.
//
//  K0: fold out_w*fuse_w -> MT16; in_w/xp_w -> bf16; x -> xhwc16 AND xwhc16.
//  K1 (53,248B LDS, 3 blk/CU): MFMA in-proj -> conv4+silu (packed) ->
//      MFMA xp-proj -> scan (2 thr/channel, packed f32, DPP pair-swap) ->
//      z-mul from regs -> YF (dir-dependent layout).
//  K3 (67,584B LDS, 2 blk/CU, 512 thr): gather, MFMA vs MT16, LN, SiLU.

typedef __attribute__((ext_vector_type(8))) short short8;
typedef __attribute__((ext_vector_type(4))) float f32x4;
typedef __attribute__((ext_vector_type(2))) float f32x2;

__device__ __forceinline__ f32x2 pk_mul(f32x2 a, f32x2 b) {
  f32x2 d;
  asm("v_pk_mul_f32 %0, %1, %2" : "=v"(d) : "v"(a), "v"(b));
  return d;
}
__device__ __forceinline__ f32x2 pk_fma(f32x2 a, f32x2 b, f32x2 c) {
  f32x2 d;
  asm("v_pk_fma_f32 %0, %1, %2, %3" : "=v"(d) : "v"(a), "v"(b), "v"(c));
  return d;
}

__device__ __forceinline__ unsigned int pk2bf(float a, float b) {
  __hip_bfloat162 h = __float22bfloat162_rn(make_float2(a, b));
  unsigned int u;
  __builtin_memcpy(&u, &h, 4);
  return u;
}
__device__ __forceinline__ unsigned short f2bf(float f) {
  __hip_bfloat16 h = __float2bfloat16(f);
  unsigned short s;
  __builtin_memcpy(&s, &h, 2);
  return s;
}
__device__ __forceinline__ float bf2f(unsigned short h) {
  return __uint_as_float(((unsigned int)h) << 16);
}
__device__ __forceinline__ float fastrcp(float x) { return __builtin_amdgcn_rcpf(x); }
__device__ __forceinline__ float siluf(float x) { return x * fastrcp(1.f + __expf(-x)); }
__device__ __forceinline__ float dpp_swap1(float x) {
  return __uint_as_float((unsigned int)__builtin_amdgcn_mov_dpp(
           (int)__float_as_uint(x), 0xB1, 0xF, 0xF, true));
}

// ---------------------------------------------------------------- K0
// blk 0..127: fold -> MT16. 128..159: in_w -> W16. 160..163: xp_w -> XW16.
// blk 164..419: x[b][c][h][w] -> xhwc16[b][h][w][c] AND xwhc16[b][w][h][c].
__global__ void k0_prep(const float* __restrict__ out_w, const float* __restrict__ fuse_w,
                        const float* __restrict__ in_w, const float* __restrict__ xp_w,
                        const float* __restrict__ x,
                        unsigned short* __restrict__ MT16, unsigned short* __restrict__ W16,
                        unsigned short* __restrict__ XW16, unsigned short* __restrict__ XH,
                        unsigned short* __restrict__ XW) {
  __shared__ unsigned short sT[64*132];   // transpose stage (blk>=164 only)
  int blk = blockIdx.x;
  int tid = threadIdx.x;
  if (blk < 128) {
    int idx = blk * 256 + tid;   // 32768
    int d   = idx & 127;
    int o   = (idx >> 7) & 63;
    int dir = idx >> 13;
    float acc = 0.f;
    #pragma unroll 8
    for (int j = 0; j < 64; ++j)
      acc += out_w[(dir*64 + j)*128 + d] * fuse_w[o*256 + dir*64 + j];
    MT16[o*512 + dir*128 + d] = f2bf(acc);   // M^T layout [o][j=dir*128+d]
  } else if (blk < 160) {
    int t = (blk - 128) * 256 + tid;
    int base = t * 8;                        // 65536 total
    float4 v0 = *(const float4*)(in_w + base);
    float4 v1 = *(const float4*)(in_w + base + 4);
    uint4 pk;
    pk.x = pk2bf(v0.x, v0.y);
    pk.y = pk2bf(v0.z, v0.w);
    pk.z = pk2bf(v1.x, v1.y);
    pk.w = pk2bf(v1.z, v1.w);
    *(uint4*)(W16 + base) = pk;
  } else if (blk < 164) {
    int t = (blk - 160) * 256 + tid;        // 1024 threads
    for (int pid = t; pid < 4*48*128; pid += 1024) {
      int dir = pid / 6144;
      int rem = pid - dir*6144;
      int row = rem >> 7, c = rem & 127;
      XW16[pid] = (row < 36) ? f2bf(xp_w[dir*4608 + row*128 + c]) : (unsigned short)0;
    }
  } else {
    int idx = blk - 164;                    // 0..255
    int b = idx >> 7, h = idx & 127;
    for (int f = tid*4; f < 8192; f += 1024) {
      int c = f >> 7, w = f & 127;
      float4 v = *(const float4*)(x + (((size_t)(b*64 + c)*128 + h)*128 + w));
      sT[c*132 + w + 0] = f2bf(v.x);
      sT[c*132 + w + 1] = f2bf(v.y);
      sT[c*132 + w + 2] = f2bf(v.z);
      sT[c*132 + w + 3] = f2bf(v.w);
    }
    __syncthreads();
    for (int f = tid*8; f < 8192; f += 2048) {
      int w = f >> 6, c0 = f & 63;
      unsigned int pk[4];
      #pragma unroll
      for (int p = 0; p < 4; ++p) {
        unsigned int lo = sT[(c0 + p*2 + 0)*132 + w];
        unsigned int hi = sT[(c0 + p*2 + 1)*132 + w];
        pk[p] = lo | (hi << 16);
      }
      uint4 v; v.x = pk[0]; v.y = pk[1]; v.z = pk[2]; v.w = pk[3];
      *(uint4*)(XH + (((size_t)(b*128 + h)*128 + w)*64 + c0)) = v;
      *(uint4*)(XW + (((size_t)(b*128 + w)*128 + h)*64 + c0)) = v;
    }
  }
}

// ---------------------------------------------------------------- K1 (fused)
// LDS (53,248 B -> 3 blocks/CU):
//   sBCf @0     18432B fp32 [128 tok][36] (B cols 0..15, C cols 16..31) [ph4+]
//   sUC  @18432 34816B bf16 [128 tok][136]; cols 0..127 = u_pre -> uc -> y;
//                      cols 128..135 = dt-rank float4 [ph4+]
// R22: XCD-aware swizzle. blockIdx round-robins XCDs (bid%8); swz gives each
// XCD a contiguous 128-block (dir,b) slice -> 2MB XH/XW window L2-resident.
__global__ __launch_bounds__(256, 3) void k1_front(
    const unsigned short* __restrict__ XH, const unsigned short* __restrict__ XW,
    const unsigned short* __restrict__ W16, const unsigned short* __restrict__ XW16,
    const float* __restrict__ conv_w, const float* __restrict__ conv_b,
    const float* __restrict__ dtp_w, const float* __restrict__ dtp_b,
    const float* __restrict__ A_log, const float* __restrict__ Dp,
    unsigned short* __restrict__ YF)
{
  __shared__ __align__(16) char smem[53248];
  float* sBCf         = (float*)smem;                      // [128][36]  (ph4+)
  unsigned short* sUC = (unsigned short*)(smem + 18432);   // [128][136]

  const int tid = threadIdx.x;
  const int bid = blockIdx.x;
  const int swz = (bid & 7) * 128 + (bid >> 3);   // bijective, XCD-contiguous
  const int dir = swz >> 8;
  const int n   = swz & 255;
  const int b   = n >> 7;
  const int r   = n & 127;
  const int n_all = dir*256 + n;

  const unsigned short* xsrc = (dir < 2 ? XH : XW) + ((size_t)(b*128 + r)*128)*64;

  const int wave = tid >> 6;
  const int lane = tid & 63;
  const int m16 = lane & 15;
  const int quad = lane >> 4;
  const int tb0 = wave * 32;
  const int st0 = tb0 + m16;          // scan-order tokens owned (B-fragment rows)
  const int st1 = tb0 + 16 + m16;
  const int sp0 = (dir & 1) ? (127 - st0) : st0;   // spatial index in xsrc
  const int sp1 = (dir & 1) ? (127 - st1) : st1;

  unsigned int zpk[2][8][2];   // silu(z) bf16-packed: [tok-half][k][pair] (32 VGPRs)

  // ---- phase 2: MFMA in-projection. A=in_w (global bf16), B=x (global bf16). ----
  {
    short8 bfr[2][2];
    #pragma unroll
    for (int ks = 0; ks < 2; ++ks) {
      bfr[0][ks] = *(const short8*)(xsrc + sp0*64 + ks*32 + quad*8);
      bfr[1][ks] = *(const short8*)(xsrc + sp1*64 + ks*32 + quad*8);
    }
    const unsigned short* Wd = W16 + (size_t)dir * 16384;

    // u rows (rt 0..7)
    for (int rt = 0; rt < 8; ++rt) {
      short8 af[2];
      #pragma unroll
      for (int ks = 0; ks < 2; ++ks)
        af[ks] = *(const short8*)(Wd + (rt*16 + m16)*64 + ks*32 + quad*8);
      #pragma unroll
      for (int tt = 0; tt < 2; ++tt) {
        f32x4 acc = {0.f, 0.f, 0.f, 0.f};
        acc = __builtin_amdgcn_mfma_f32_16x16x32_bf16(af[0], bfr[tt][0], acc, 0, 0, 0);
        acc = __builtin_amdgcn_mfma_f32_16x16x32_bf16(af[1], bfr[tt][1], acc, 0, 0, 0);
        const int tok = tt ? st1 : st0;
        const int r0 = rt*16 + quad*4;
        uint2 u2;
        u2.x = pk2bf(acc[0], acc[1]);
        u2.y = pk2bf(acc[2], acc[3]);
        *(uint2*)(sUC + tok*136 + r0) = u2;
      }
    }
    // z rows (rt 8..15) -> registers
    #pragma unroll
    for (int k = 0; k < 8; ++k) {
      short8 af[2];
      #pragma unroll
      for (int ks = 0; ks < 2; ++ks)
        af[ks] = *(const short8*)(Wd + ((8+k)*16 + m16)*64 + ks*32 + quad*8);
      #pragma unroll
      for (int tt = 0; tt < 2; ++tt) {
        f32x4 acc = {0.f, 0.f, 0.f, 0.f};
        acc = __builtin_amdgcn_mfma_f32_16x16x32_bf16(af[0], bfr[tt][0], acc, 0, 0, 0);
        acc = __builtin_amdgcn_mfma_f32_16x16x32_bf16(af[1], bfr[tt][1], acc, 0, 0, 0);
        zpk[tt][k][0] = pk2bf(siluf(acc[0]), siluf(acc[1]));
        zpk[tt][k][1] = pk2bf(siluf(acc[2]), siluf(acc[3]));
      }
    }
  }
  __syncthreads();

  // ---- phase 3: causal conv-4 + silu in sUC (bf16), packed 2-chunk. ----
  {
    const int d = tid & 127;
    const int half = tid >> 7;
    const int ca = half * 32;          // chunk A: 0 or 32
    const int cb2 = (half + 2) * 32;   // chunk B: 64 or 96
    const float* cw = conv_w + (size_t)(dir*128 + d)*4;
    const float c0w = cw[0], c1w = cw[1], c2w = cw[2], c3w = cw[3];
    const float cbv = conv_b[dir*128 + d];
    const f32x2 cw0v = {c0w, c0w}, cw1v = {c1w, c1w}, cw2v = {c2w, c2w}, cw3v = {c3w, c3w};
    const f32x2 cbv2 = {cbv, cbv};
    f32x2 A0 = { half ? bf2f(sUC[(ca-3)*136 + d]) : 0.f, bf2f(sUC[(cb2-3)*136 + d]) };
    f32x2 A1 = { half ? bf2f(sUC[(ca-2)*136 + d]) : 0.f, bf2f(sUC[(cb2-2)*136 + d]) };
    f32x2 A2 = { half ? bf2f(sUC[(ca-1)*136 + d]) : 0.f, bf2f(sUC[(cb2-1)*136 + d]) };
    __syncthreads();
    unsigned short* pa = sUC + ca*136 + d;
    unsigned short* pb = sUC + cb2*136 + d;
    for (int i = 0; i < 32; ++i) {
      f32x2 cur = { bf2f(*pa), bf2f(*pb) };
      f32x2 v = pk_fma(cw3v, cur,
                pk_fma(cw2v, A2,
                pk_fma(cw1v, A1,
                pk_fma(cw0v, A0, cbv2))));
      *pa = f2bf(siluf(v.x));
      *pb = f2bf(siluf(v.y));
      A0 = A1; A1 = A2; A2 = cur;
      pa += 136; pb += 136;
    }
  }
  __syncthreads();

  // ---- phase 4: MFMA xp-projection. A=xp_w (global bf16), B=uc (LDS sUC). ----
  {
    short8 bfr[2][4];
    #pragma unroll
    for (int tt = 0; tt < 2; ++tt)
      #pragma unroll
      for (int ks = 0; ks < 4; ++ks)
        bfr[tt][ks] = *(const short8*)(sUC + (tt ? st1 : st0)*136 + ks*32 + quad*8);

    const unsigned short* XWd = XW16 + (size_t)dir * (48*128);

    for (int rt = 0; rt < 3; ++rt) {
      short8 af[4];
      #pragma unroll
      for (int ks = 0; ks < 4; ++ks)
        af[ks] = *(const short8*)(XWd + (rt*16 + m16)*128 + ks*32 + quad*8);
      #pragma unroll
      for (int tt = 0; tt < 2; ++tt) {
        f32x4 acc = {0.f, 0.f, 0.f, 0.f};
        #pragma unroll
        for (int ks = 0; ks < 4; ++ks)
          acc = __builtin_amdgcn_mfma_f32_16x16x32_bf16(af[ks], bfr[tt][ks], acc, 0, 0, 0);
        const int tok = tt ? st1 : st0;
        const int r0 = rt*16 + quad*4;   // 0,4,...,44
        if (r0 == 0) {
          float4 v; v.x = acc[0]; v.y = acc[1]; v.z = acc[2]; v.w = acc[3];
          *(float4*)(smem + 18432 + tok*272 + 256) = v;      // sUC cols 128..135
        } else if (r0 < 36) {
          float4 v; v.x = acc[0]; v.y = acc[1]; v.z = acc[2]; v.w = acc[3];
          *(float4*)(sBCf + tok*36 + (r0 - 4)) = v;          // B: 0..15, C: 16..31
        }
      }
    }
  }
  __syncthreads();

  // ---- phase 5: selective scan, 2 threads/channel (8 states each). ----
  //      Packed f32 state math (v_pk_*), DPP quad-perm pair-swap, uncond store.
  {
    const int d = tid >> 1;
    const int p = tid & 1;
    const float* dwp = dtp_w + (size_t)(dir*128 + d) * 4;
    const float dw0 = dwp[0], dw1 = dwp[1], dw2 = dwp[2], dw3 = dwp[3];
    const float db = dtp_b[dir*128 + d];
    const float dpv = Dp[dir*128 + d];

    float Av[8];
    bool fast = true;
    #pragma unroll
    for (int j = 0; j < 8; ++j) {
      float a = -__expf(A_log[((size_t)(dir*128 + d))*16 + p*8 + j]);
      Av[j] = a;
      if (fabsf((-a) - (float)(p*8 + j + 1)) > 1e-3f) fast = false;
    }

    if (fast) {
      // E = exp(-softplus(dr)) = 1/(1+exp(dr)); e_j = E^(p*8+j+1).
      f32x2 h0 = {0.f, 0.f}, h1 = {0.f, 0.f}, h2v = {0.f, 0.f}, h3 = {0.f, 0.f};
      const char* qp = smem + 18432 + 256;             // dt float4, +272/tok
      const float* bp = sBCf + p*8;                    // B pairs, +36/tok
      const float* cp = sBCf + 16 + p*8;               // C pairs, +36/tok
      const unsigned short* up = sUC + d;              // u,  +136/tok
      unsigned short* yo = sUC + d;                    // y,  +136/tok
      for (int l = 0; l < 128; ++l) {
        float4 Q = *(const float4*)qp;
        f32x2 B01 = *(const f32x2*)(bp + 0), B23 = *(const f32x2*)(bp + 2);
        f32x2 B45 = *(const f32x2*)(bp + 4), B67 = *(const f32x2*)(bp + 6);
        f32x2 C01 = *(const f32x2*)(cp + 0), C23 = *(const f32x2*)(cp + 2);
        f32x2 C45 = *(const f32x2*)(cp + 4), C67 = *(const f32x2*)(cp + 6);
        float u = bf2f(*up);
        float dr = Q.x*dw0 + Q.y*dw1 + Q.z*dw2 + Q.w*dw3 + db;
        float te = __expf(dr);
        float dt = (dr > 20.f) ? dr : __logf(1.f + te);
        float dtu = dt * u;
        float E = fastrcp(1.f + te);
        float E2 = E*E, E4 = E2*E2, E8 = E4*E4;
        float eb = p ? E8 : 1.f;
        f32x2 P0 = {E*eb, E2*eb};
        f32x2 E2v = {E2, E2};
        f32x2 P1 = pk_mul(P0, E2v);
        f32x2 P2 = pk_mul(P1, E2v);
        f32x2 P3 = pk_mul(P2, E2v);
        f32x2 du = {dtu, dtu};
        h0  = pk_fma(h0,  P0, pk_mul(du, B01));
        h1  = pk_fma(h1,  P1, pk_mul(du, B23));
        h2v = pk_fma(h2v, P2, pk_mul(du, B45));
        h3  = pk_fma(h3,  P3, pk_mul(du, B67));
        f32x2 ya = pk_mul(h0, C01);
        f32x2 yb = pk_mul(h1, C23);
        ya = pk_fma(h2v, C45, ya);
        yb = pk_fma(h3,  C67, yb);
        float ypar = (ya.x + ya.y) + (yb.x + yb.y);
        // pair-swap within quad: lane^1 (p0<->p1), 1 VALU via DPP quad_perm
        float ot = dpp_swap1(ypar);
        float ysum = ypar + ot;                  // bit-identical on both lanes
        *yo = f2bf(ysum + u*dpv);                // same value, same addr: benign
        qp += 272; bp += 36; cp += 36; up += 136; yo += 136;
      }
    } else {
      float h[8];
      #pragma unroll
      for (int j = 0; j < 8; ++j) h[j] = 0.f;
      for (int l = 0; l < 128; ++l) {
        float4 Q = *(const float4*)(smem + 18432 + l*272 + 256);
        float4 b0 = *(const float4*)(sBCf + l*36 + p*8);
        float4 b1 = *(const float4*)(sBCf + l*36 + p*8 + 4);
        float4 c0 = *(const float4*)(sBCf + l*36 + 16 + p*8);
        float4 c1 = *(const float4*)(sBCf + l*36 + 16 + p*8 + 4);
        float Bv[8] = {b0.x,b0.y,b0.z,b0.w, b1.x,b1.y,b1.z,b1.w};
        float Cv[8] = {c0.x,c0.y,c0.z,c0.w, c1.x,c1.y,c1.z,c1.w};
        float u = bf2f(sUC[l*136 + d]);
        float dr = Q.x*dw0 + Q.y*dw1 + Q.z*dw2 + Q.w*dw3 + db;
        float te = __expf(dr);
        float dt = (dr > 20.f) ? dr : __logf(1.f + te);
        float dtu = dt * u;
        float yp = 0.f;
        #pragma unroll
        for (int j = 0; j < 8; ++j) {
          float ej = __expf(dt*Av[j]);
          h[j] = h[j]*ej + dtu*Bv[j];
          yp += h[j]*Cv[j];
        }
        float ot = dpp_swap1(yp);
        float ysum = yp + ot;
        if (p == 0) sUC[l*136 + d] = f2bf(ysum + u*dpv);
      }
    }
  }
  __syncthreads();

  // ---- phase 6: yf = y * silu(z) from registers; dir-dependent YF layout. ----
  #pragma unroll
  for (int tt = 0; tt < 2; ++tt) {
    const int st = tt ? st1 : st0;
    size_t rowbase;
    if (dir < 2)       rowbase = ((size_t)n_all*128 + st)*128;
    else if (dir == 2) rowbase = ((size_t)(512 + b*128 + st)*128 + r)*128;
    else               rowbase = ((size_t)(768 + b*128 + (127-st))*128 + r)*128;
    #pragma unroll
    for (int k = 0; k < 8; ++k) {
      const int dz = 16*k + quad*4;
      uint2 yv = *(const uint2*)(sUC + st*136 + dz);
      float y0 = __uint_as_float(yv.x << 16);
      float y1 = __uint_as_float(yv.x & 0xffff0000u);
      float y2 = __uint_as_float(yv.y << 16);
      float y3 = __uint_as_float(yv.y & 0xffff0000u);
      unsigned int z01 = zpk[tt][k][0], z23 = zpk[tt][k][1];
      float z0 = __uint_as_float(z01 << 16);
      float z1 = __uint_as_float(z01 & 0xffff0000u);
      float z2 = __uint_as_float(z23 << 16);
      float z3 = __uint_as_float(z23 & 0xffff0000u);
      uint2 ov;
      ov.x = pk2bf(y0*z0, y1*z1);
      ov.y = pk2bf(y2*z2, y3*z3);
      *(uint2*)(YF + rowbase + dz) = ov;
    }
  }
}

// ---------------------------------------------------------------- K3 (MFMA fuse + LN)
// 512 threads, 2 blocks/CU -> 16 waves/CU. Grid 512 = 1 resident round.
__global__ __launch_bounds__(512, 2) void k3_fuse(
    const unsigned short* __restrict__ YF, const unsigned short* __restrict__ MT16,
    const float* __restrict__ fuse_b, const float* __restrict__ ln_g,
    const float* __restrict__ ln_b, float* __restrict__ out)
{
  __shared__ __align__(16) unsigned short sYB[64*520];   // 66,560 B
  __shared__ float sLN[2][64][2];                        //  1,024 B

  const int tid = threadIdx.x;
  const int blk = blockIdx.x;             // 512
  const int b = blk >> 8;
  const int rr2 = blk & 255;
  const int h = rr2 >> 1;
  const int w0 = (rr2 & 1) * 64;

  for (int f = tid*8; f < 32768; f += 4096) {
    int dirg = f >> 13;
    int rem = f & 8191;
    int tok = rem >> 7;
    int dd = rem & 127;
    int X = (dirg == 1) ? (127 - w0 - tok) : (w0 + tok);
    size_t base = ((size_t)(dirg*256 + b*128 + h)*128 + X)*128 + dd;
    *(uint4*)(sYB + tok*520 + dirg*128 + dd) = *(const uint4*)(YF + base);
  }
  __syncthreads();

  const int wave = tid >> 6;     // 0..7
  const int lane = tid & 63;
  const int m16 = lane & 15;
  const int quad = lane >> 4;
  const int tg   = wave & 3;     // token group
  const int mh   = wave >> 2;    // mt half: 0 -> mt{0,1}, 1 -> mt{2,3}
  const int tok  = tg*16 + m16;

  short8 bfr[16];
  #pragma unroll
  for (int jt = 0; jt < 16; ++jt)
    bfr[jt] = *(const short8*)(sYB + tok*520 + jt*32 + quad*8);

  float facc[2][4];
  #pragma unroll
  for (int mi = 0; mi < 2; ++mi) {
    const int mt = mh*2 + mi;
    f32x4 acc = {0.f, 0.f, 0.f, 0.f};
    #pragma unroll
    for (int jt = 0; jt < 16; ++jt) {
      short8 af = *(const short8*)(MT16 + (size_t)(mt*16 + m16)*512 + jt*32 + quad*8);
      acc = __builtin_amdgcn_mfma_f32_16x16x32_bf16(af, bfr[jt], acc, 0, 0, 0);
    }
    facc[mi][0] = acc[0]; facc[mi][1] = acc[1]; facc[mi][2] = acc[2]; facc[mi][3] = acc[3];
  }

  float fv[8];
  float s1 = 0.f, s2 = 0.f;
  #pragma unroll
  for (int mi = 0; mi < 2; ++mi)
    #pragma unroll
    for (int rr = 0; rr < 4; ++rr) {
      int o = (mh*2 + mi)*16 + quad*4 + rr;
      float v = facc[mi][rr] + fuse_b[o];
      fv[mi*4 + rr] = v;
      s1 += v; s2 += v*v;
    }
  s1 += __shfl_xor(s1, 16, 64); s1 += __shfl_xor(s1, 32, 64);
  s2 += __shfl_xor(s2, 16, 64); s2 += __shfl_xor(s2, 32, 64);
  if (lane < 16) {
    sLN[mh][tok][0] = s1;
    sLN[mh][tok][1] = s2;
  }
  __syncthreads();
  float t1 = s1 + sLN[1 - mh][tok][0];
  float t2 = s2 + sLN[1 - mh][tok][1];
  float mu = t1 * (1.f/64.f);
  float var = t2 * (1.f/64.f) - mu*mu;
  float rs = rsqrtf(var + 1e-5f);

  #pragma unroll
  for (int mi = 0; mi < 2; ++mi)
    #pragma unroll
    for (int rr = 0; rr < 4; ++rr) {
      int o = (mh*2 + mi)*16 + quad*4 + rr;
      float v = (fv[mi*4 + rr] - mu) * rs * ln_g[o] + ln_b[o];
      out[((size_t)(b*64 + o)*128 + h)*128 + (w0 + tok)] = siluf(v);
    }
}

// ---------------------------------------------------------------- host
extern "C" void kernel_launch(void* const* d_in, const int* in_sizes, int n_in,
                              void* d_out, int out_size, void* d_ws, size_t ws_size,
                              hipStream_t stream) {
  const float* x      = (const float*)d_in[0];
  const float* in_w   = (const float*)d_in[1];
  const float* conv_w = (const float*)d_in[2];
  const float* conv_b = (const float*)d_in[3];
  const float* xp_w   = (const float*)d_in[4];
  const float* dtp_w  = (const float*)d_in[5];
  const float* dtp_b  = (const float*)d_in[6];
  const float* A_log  = (const float*)d_in[7];
  const float* Dp     = (const float*)d_in[8];
  const float* out_w  = (const float*)d_in[9];
  const float* fuse_w = (const float*)d_in[10];
  const float* fuse_b = (const float*)d_in[11];
  const float* ln_g   = (const float*)d_in[12];
  const float* ln_b   = (const float*)d_in[13];
  float* out = (float*)d_out;

  // ws layout (BYTES):
  char* ws = (char*)d_ws;
  unsigned short* YF   = (unsigned short*)(ws);              // 33,554,432 (yf, dir-layouts)
  unsigned short* MT16 = (unsigned short*)(ws + 33554432);   //     65,536
  unsigned short* W16  = (unsigned short*)(ws + 33619968);   //    131,072
  unsigned short* XW16 = (unsigned short*)(ws + 33751040);   //     49,152
  unsigned short* XH   = (unsigned short*)(ws + 33800192);   //  4,194,304 (xhwc16)
  unsigned short* XWt  = (unsigned short*)(ws + 37994496);   //  4,194,304 (xwhc16)
  // total 42,188,800 B

  k0_prep<<<dim3(420), dim3(256), 0, stream>>>(out_w, fuse_w, in_w, xp_w, x,
                                               MT16, W16, XW16, XH, XWt);
  k1_front<<<dim3(1024), dim3(256), 0, stream>>>(XH, XWt, W16, XW16, conv_w, conv_b,
                                                 dtp_w, dtp_b, A_log, Dp, YF);
  k3_fuse<<<dim3(512), dim3(512), 0, stream>>>(YF, MT16, fuse_b, ln_g, ln_b, out);
}

// Round 12
// 205.328 us; speedup vs baseline: 1.1345x; 1.0004x over previous
//
#include <hip/hip_runtime.h>
#include <hip/hip_bf16.h>
#include <math.h>

// MambaBlock: 4-direction 2D selective scan + fuse + LN + SiLU
// B=2, H=W=128, D_MODEL=64, D_INNER=128, D_STATE=16, DT_RANK=4, D_CONV=4
//
// R23 = k3 occupancy retile. Ledger fact: rest = total - k1 = ~99us in EVERY
// round (R14/R16/R19/R22), launch overhead negligible (R19: +1 launch, same
// rest) -> k0+k3 really execute ~99us despite moving <50MB each => latency/
// occupancy-bound. k3 was the suspect: 66.5KB LDS -> 2 blk/CU, bfr[16] (64
// VGPR) live across 4 mt. Now: 32-token tiles (grid 1024, sYB 33,280B), each
// wave owns ONE mt -> bfr streamed (1 live fragment), ~50 VGPR, and
// launch_bounds(512,8) targets VGPR<=64 -> 4 blk/CU = 32 waves/CU, one
// uniform round, half the per-block gather latency chain. LN via 4-way
// cross-wave LDS reduce. Math identical.
// k1 = R22 (frozen: 103us, swizzle kept). k0 unchanged.
//
//  K0: fold out_w*fuse_w -> MT16; in_w/xp_w -> bf16; x -> xhwc16 AND xwhc16.
//  K1 (53,248B LDS, 3 blk/CU): MFMA in-proj -> conv4+silu (packed) ->
//      MFMA xp-proj -> scan (2 thr/channel, packed f32, DPP pair-swap) ->
//      z-mul from regs -> YF (dir-dependent layout).
//  K3 (34,304B LDS, 4 blk/CU, 512 thr, 1024 blocks): gather 32-tok tile,
//      1 mt/wave streamed MFMA, 4-way LN reduce, SiLU.

typedef __attribute__((ext_vector_type(8))) short short8;
typedef __attribute__((ext_vector_type(4))) float f32x4;
typedef __attribute__((ext_vector_type(2))) float f32x2;

__device__ __forceinline__ f32x2 pk_mul(f32x2 a, f32x2 b) {
  f32x2 d;
  asm("v_pk_mul_f32 %0, %1, %2" : "=v"(d) : "v"(a), "v"(b));
  return d;
}
__device__ __forceinline__ f32x2 pk_fma(f32x2 a, f32x2 b, f32x2 c) {
  f32x2 d;
  asm("v_pk_fma_f32 %0, %1, %2, %3" : "=v"(d) : "v"(a), "v"(b), "v"(c));
  return d;
}

__device__ __forceinline__ unsigned int pk2bf(float a, float b) {
  __hip_bfloat162 h = __float22bfloat162_rn(make_float2(a, b));
  unsigned int u;
  __builtin_memcpy(&u, &h, 4);
  return u;
}
__device__ __forceinline__ unsigned short f2bf(float f) {
  __hip_bfloat16 h = __float2bfloat16(f);
  unsigned short s;
  __builtin_memcpy(&s, &h, 2);
  return s;
}
__device__ __forceinline__ float bf2f(unsigned short h) {
  return __uint_as_float(((unsigned int)h) << 16);
}
__device__ __forceinline__ float fastrcp(float x) { return __builtin_amdgcn_rcpf(x); }
__device__ __forceinline__ float siluf(float x) { return x * fastrcp(1.f + __expf(-x)); }
__device__ __forceinline__ float dpp_swap1(float x) {
  return __uint_as_float((unsigned int)__builtin_amdgcn_mov_dpp(
           (int)__float_as_uint(x), 0xB1, 0xF, 0xF, true));
}

// ---------------------------------------------------------------- K0
// blk 0..127: fold -> MT16. 128..159: in_w -> W16. 160..163: xp_w -> XW16.
// blk 164..419: x[b][c][h][w] -> xhwc16[b][h][w][c] AND xwhc16[b][w][h][c].
__global__ void k0_prep(const float* __restrict__ out_w, const float* __restrict__ fuse_w,
                        const float* __restrict__ in_w, const float* __restrict__ xp_w,
                        const float* __restrict__ x,
                        unsigned short* __restrict__ MT16, unsigned short* __restrict__ W16,
                        unsigned short* __restrict__ XW16, unsigned short* __restrict__ XH,
                        unsigned short* __restrict__ XW) {
  __shared__ unsigned short sT[64*132];   // transpose stage (blk>=164 only)
  int blk = blockIdx.x;
  int tid = threadIdx.x;
  if (blk < 128) {
    int idx = blk * 256 + tid;   // 32768
    int d   = idx & 127;
    int o   = (idx >> 7) & 63;
    int dir = idx >> 13;
    float acc = 0.f;
    #pragma unroll 8
    for (int j = 0; j < 64; ++j)
      acc += out_w[(dir*64 + j)*128 + d] * fuse_w[o*256 + dir*64 + j];
    MT16[o*512 + dir*128 + d] = f2bf(acc);   // M^T layout [o][j=dir*128+d]
  } else if (blk < 160) {
    int t = (blk - 128) * 256 + tid;
    int base = t * 8;                        // 65536 total
    float4 v0 = *(const float4*)(in_w + base);
    float4 v1 = *(const float4*)(in_w + base + 4);
    uint4 pk;
    pk.x = pk2bf(v0.x, v0.y);
    pk.y = pk2bf(v0.z, v0.w);
    pk.z = pk2bf(v1.x, v1.y);
    pk.w = pk2bf(v1.z, v1.w);
    *(uint4*)(W16 + base) = pk;
  } else if (blk < 164) {
    int t = (blk - 160) * 256 + tid;        // 1024 threads
    for (int pid = t; pid < 4*48*128; pid += 1024) {
      int dir = pid / 6144;
      int rem = pid - dir*6144;
      int row = rem >> 7, c = rem & 127;
      XW16[pid] = (row < 36) ? f2bf(xp_w[dir*4608 + row*128 + c]) : (unsigned short)0;
    }
  } else {
    int idx = blk - 164;                    // 0..255
    int b = idx >> 7, h = idx & 127;
    for (int f = tid*4; f < 8192; f += 1024) {
      int c = f >> 7, w = f & 127;
      float4 v = *(const float4*)(x + (((size_t)(b*64 + c)*128 + h)*128 + w));
      sT[c*132 + w + 0] = f2bf(v.x);
      sT[c*132 + w + 1] = f2bf(v.y);
      sT[c*132 + w + 2] = f2bf(v.z);
      sT[c*132 + w + 3] = f2bf(v.w);
    }
    __syncthreads();
    for (int f = tid*8; f < 8192; f += 2048) {
      int w = f >> 6, c0 = f & 63;
      unsigned int pk[4];
      #pragma unroll
      for (int p = 0; p < 4; ++p) {
        unsigned int lo = sT[(c0 + p*2 + 0)*132 + w];
        unsigned int hi = sT[(c0 + p*2 + 1)*132 + w];
        pk[p] = lo | (hi << 16);
      }
      uint4 v; v.x = pk[0]; v.y = pk[1]; v.z = pk[2]; v.w = pk[3];
      *(uint4*)(XH + (((size_t)(b*128 + h)*128 + w)*64 + c0)) = v;
      *(uint4*)(XW + (((size_t)(b*128 + w)*128 + h)*64 + c0)) = v;
    }
  }
}

// ---------------------------------------------------------------- K1 (fused)
// LDS (53,248 B -> 3 blocks/CU):
//   sBCf @0     18432B fp32 [128 tok][36] (B cols 0..15, C cols 16..31) [ph4+]
//   sUC  @18432 34816B bf16 [128 tok][136]; cols 0..127 = u_pre -> uc -> y;
//                      cols 128..135 = dt-rank float4 [ph4+]
// XCD-aware swizzle (R22): each XCD gets a contiguous 128-block (dir,b) slice.
__global__ __launch_bounds__(256, 3) void k1_front(
    const unsigned short* __restrict__ XH, const unsigned short* __restrict__ XW,
    const unsigned short* __restrict__ W16, const unsigned short* __restrict__ XW16,
    const float* __restrict__ conv_w, const float* __restrict__ conv_b,
    const float* __restrict__ dtp_w, const float* __restrict__ dtp_b,
    const float* __restrict__ A_log, const float* __restrict__ Dp,
    unsigned short* __restrict__ YF)
{
  __shared__ __align__(16) char smem[53248];
  float* sBCf         = (float*)smem;                      // [128][36]  (ph4+)
  unsigned short* sUC = (unsigned short*)(smem + 18432);   // [128][136]

  const int tid = threadIdx.x;
  const int bid = blockIdx.x;
  const int swz = (bid & 7) * 128 + (bid >> 3);   // bijective, XCD-contiguous
  const int dir = swz >> 8;
  const int n   = swz & 255;
  const int b   = n >> 7;
  const int r   = n & 127;
  const int n_all = dir*256 + n;

  const unsigned short* xsrc = (dir < 2 ? XH : XW) + ((size_t)(b*128 + r)*128)*64;

  const int wave = tid >> 6;
  const int lane = tid & 63;
  const int m16 = lane & 15;
  const int quad = lane >> 4;
  const int tb0 = wave * 32;
  const int st0 = tb0 + m16;          // scan-order tokens owned (B-fragment rows)
  const int st1 = tb0 + 16 + m16;
  const int sp0 = (dir & 1) ? (127 - st0) : st0;   // spatial index in xsrc
  const int sp1 = (dir & 1) ? (127 - st1) : st1;

  unsigned int zpk[2][8][2];   // silu(z) bf16-packed: [tok-half][k][pair] (32 VGPRs)

  // ---- phase 2: MFMA in-projection. A=in_w (global bf16), B=x (global bf16). ----
  {
    short8 bfr[2][2];
    #pragma unroll
    for (int ks = 0; ks < 2; ++ks) {
      bfr[0][ks] = *(const short8*)(xsrc + sp0*64 + ks*32 + quad*8);
      bfr[1][ks] = *(const short8*)(xsrc + sp1*64 + ks*32 + quad*8);
    }
    const unsigned short* Wd = W16 + (size_t)dir * 16384;

    // u rows (rt 0..7)
    for (int rt = 0; rt < 8; ++rt) {
      short8 af[2];
      #pragma unroll
      for (int ks = 0; ks < 2; ++ks)
        af[ks] = *(const short8*)(Wd + (rt*16 + m16)*64 + ks*32 + quad*8);
      #pragma unroll
      for (int tt = 0; tt < 2; ++tt) {
        f32x4 acc = {0.f, 0.f, 0.f, 0.f};
        acc = __builtin_amdgcn_mfma_f32_16x16x32_bf16(af[0], bfr[tt][0], acc, 0, 0, 0);
        acc = __builtin_amdgcn_mfma_f32_16x16x32_bf16(af[1], bfr[tt][1], acc, 0, 0, 0);
        const int tok = tt ? st1 : st0;
        const int r0 = rt*16 + quad*4;
        uint2 u2;
        u2.x = pk2bf(acc[0], acc[1]);
        u2.y = pk2bf(acc[2], acc[3]);
        *(uint2*)(sUC + tok*136 + r0) = u2;
      }
    }
    // z rows (rt 8..15) -> registers
    #pragma unroll
    for (int k = 0; k < 8; ++k) {
      short8 af[2];
      #pragma unroll
      for (int ks = 0; ks < 2; ++ks)
        af[ks] = *(const short8*)(Wd + ((8+k)*16 + m16)*64 + ks*32 + quad*8);
      #pragma unroll
      for (int tt = 0; tt < 2; ++tt) {
        f32x4 acc = {0.f, 0.f, 0.f, 0.f};
        acc = __builtin_amdgcn_mfma_f32_16x16x32_bf16(af[0], bfr[tt][0], acc, 0, 0, 0);
        acc = __builtin_amdgcn_mfma_f32_16x16x32_bf16(af[1], bfr[tt][1], acc, 0, 0, 0);
        zpk[tt][k][0] = pk2bf(siluf(acc[0]), siluf(acc[1]));
        zpk[tt][k][1] = pk2bf(siluf(acc[2]), siluf(acc[3]));
      }
    }
  }
  __syncthreads();

  // ---- phase 3: causal conv-4 + silu in sUC (bf16), packed 2-chunk. ----
  {
    const int d = tid & 127;
    const int half = tid >> 7;
    const int ca = half * 32;          // chunk A: 0 or 32
    const int cb2 = (half + 2) * 32;   // chunk B: 64 or 96
    const float* cw = conv_w + (size_t)(dir*128 + d)*4;
    const float c0w = cw[0], c1w = cw[1], c2w = cw[2], c3w = cw[3];
    const float cbv = conv_b[dir*128 + d];
    const f32x2 cw0v = {c0w, c0w}, cw1v = {c1w, c1w}, cw2v = {c2w, c2w}, cw3v = {c3w, c3w};
    const f32x2 cbv2 = {cbv, cbv};
    f32x2 A0 = { half ? bf2f(sUC[(ca-3)*136 + d]) : 0.f, bf2f(sUC[(cb2-3)*136 + d]) };
    f32x2 A1 = { half ? bf2f(sUC[(ca-2)*136 + d]) : 0.f, bf2f(sUC[(cb2-2)*136 + d]) };
    f32x2 A2 = { half ? bf2f(sUC[(ca-1)*136 + d]) : 0.f, bf2f(sUC[(cb2-1)*136 + d]) };
    __syncthreads();
    unsigned short* pa = sUC + ca*136 + d;
    unsigned short* pb = sUC + cb2*136 + d;
    for (int i = 0; i < 32; ++i) {
      f32x2 cur = { bf2f(*pa), bf2f(*pb) };
      f32x2 v = pk_fma(cw3v, cur,
                pk_fma(cw2v, A2,
                pk_fma(cw1v, A1,
                pk_fma(cw0v, A0, cbv2))));
      *pa = f2bf(siluf(v.x));
      *pb = f2bf(siluf(v.y));
      A0 = A1; A1 = A2; A2 = cur;
      pa += 136; pb += 136;
    }
  }
  __syncthreads();

  // ---- phase 4: MFMA xp-projection. A=xp_w (global bf16), B=uc (LDS sUC). ----
  {
    short8 bfr[2][4];
    #pragma unroll
    for (int tt = 0; tt < 2; ++tt)
      #pragma unroll
      for (int ks = 0; ks < 4; ++ks)
        bfr[tt][ks] = *(const short8*)(sUC + (tt ? st1 : st0)*136 + ks*32 + quad*8);

    const unsigned short* XWd = XW16 + (size_t)dir * (48*128);

    for (int rt = 0; rt < 3; ++rt) {
      short8 af[4];
      #pragma unroll
      for (int ks = 0; ks < 4; ++ks)
        af[ks] = *(const short8*)(XWd + (rt*16 + m16)*128 + ks*32 + quad*8);
      #pragma unroll
      for (int tt = 0; tt < 2; ++tt) {
        f32x4 acc = {0.f, 0.f, 0.f, 0.f};
        #pragma unroll
        for (int ks = 0; ks < 4; ++ks)
          acc = __builtin_amdgcn_mfma_f32_16x16x32_bf16(af[ks], bfr[tt][ks], acc, 0, 0, 0);
        const int tok = tt ? st1 : st0;
        const int r0 = rt*16 + quad*4;   // 0,4,...,44
        if (r0 == 0) {
          float4 v; v.x = acc[0]; v.y = acc[1]; v.z = acc[2]; v.w = acc[3];
          *(float4*)(smem + 18432 + tok*272 + 256) = v;      // sUC cols 128..135
        } else if (r0 < 36) {
          float4 v; v.x = acc[0]; v.y = acc[1]; v.z = acc[2]; v.w = acc[3];
          *(float4*)(sBCf + tok*36 + (r0 - 4)) = v;          // B: 0..15, C: 16..31
        }
      }
    }
  }
  __syncthreads();

  // ---- phase 5: selective scan, 2 threads/channel (8 states each). ----
  //      Packed f32 state math (v_pk_*), DPP quad-perm pair-swap, uncond store.
  {
    const int d = tid >> 1;
    const int p = tid & 1;
    const float* dwp = dtp_w + (size_t)(dir*128 + d) * 4;
    const float dw0 = dwp[0], dw1 = dwp[1], dw2 = dwp[2], dw3 = dwp[3];
    const float db = dtp_b[dir*128 + d];
    const float dpv = Dp[dir*128 + d];

    float Av[8];
    bool fast = true;
    #pragma unroll
    for (int j = 0; j < 8; ++j) {
      float a = -__expf(A_log[((size_t)(dir*128 + d))*16 + p*8 + j]);
      Av[j] = a;
      if (fabsf((-a) - (float)(p*8 + j + 1)) > 1e-3f) fast = false;
    }

    if (fast) {
      // E = exp(-softplus(dr)) = 1/(1+exp(dr)); e_j = E^(p*8+j+1).
      f32x2 h0 = {0.f, 0.f}, h1 = {0.f, 0.f}, h2v = {0.f, 0.f}, h3 = {0.f, 0.f};
      const char* qp = smem + 18432 + 256;             // dt float4, +272/tok
      const float* bp = sBCf + p*8;                    // B pairs, +36/tok
      const float* cp = sBCf + 16 + p*8;               // C pairs, +36/tok
      const unsigned short* up = sUC + d;              // u,  +136/tok
      unsigned short* yo = sUC + d;                    // y,  +136/tok
      for (int l = 0; l < 128; ++l) {
        float4 Q = *(const float4*)qp;
        f32x2 B01 = *(const f32x2*)(bp + 0), B23 = *(const f32x2*)(bp + 2);
        f32x2 B45 = *(const f32x2*)(bp + 4), B67 = *(const f32x2*)(bp + 6);
        f32x2 C01 = *(const f32x2*)(cp + 0), C23 = *(const f32x2*)(cp + 2);
        f32x2 C45 = *(const f32x2*)(cp + 4), C67 = *(const f32x2*)(cp + 6);
        float u = bf2f(*up);
        float dr = Q.x*dw0 + Q.y*dw1 + Q.z*dw2 + Q.w*dw3 + db;
        float te = __expf(dr);
        float dt = (dr > 20.f) ? dr : __logf(1.f + te);
        float dtu = dt * u;
        float E = fastrcp(1.f + te);
        float E2 = E*E, E4 = E2*E2, E8 = E4*E4;
        float eb = p ? E8 : 1.f;
        f32x2 P0 = {E*eb, E2*eb};
        f32x2 E2v = {E2, E2};
        f32x2 P1 = pk_mul(P0, E2v);
        f32x2 P2 = pk_mul(P1, E2v);
        f32x2 P3 = pk_mul(P2, E2v);
        f32x2 du = {dtu, dtu};
        h0  = pk_fma(h0,  P0, pk_mul(du, B01));
        h1  = pk_fma(h1,  P1, pk_mul(du, B23));
        h2v = pk_fma(h2v, P2, pk_mul(du, B45));
        h3  = pk_fma(h3,  P3, pk_mul(du, B67));
        f32x2 ya = pk_mul(h0, C01);
        f32x2 yb = pk_mul(h1, C23);
        ya = pk_fma(h2v, C45, ya);
        yb = pk_fma(h3,  C67, yb);
        float ypar = (ya.x + ya.y) + (yb.x + yb.y);
        // pair-swap within quad: lane^1 (p0<->p1), 1 VALU via DPP quad_perm
        float ot = dpp_swap1(ypar);
        float ysum = ypar + ot;                  // bit-identical on both lanes
        *yo = f2bf(ysum + u*dpv);                // same value, same addr: benign
        qp += 272; bp += 36; cp += 36; up += 136; yo += 136;
      }
    } else {
      float h[8];
      #pragma unroll
      for (int j = 0; j < 8; ++j) h[j] = 0.f;
      for (int l = 0; l < 128; ++l) {
        float4 Q = *(const float4*)(smem + 18432 + l*272 + 256);
        float4 b0 = *(const float4*)(sBCf + l*36 + p*8);
        float4 b1 = *(const float4*)(sBCf + l*36 + p*8 + 4);
        float4 c0 = *(const float4*)(sBCf + l*36 + 16 + p*8);
        float4 c1 = *(const float4*)(sBCf + l*36 + 16 + p*8 + 4);
        float Bv[8] = {b0.x,b0.y,b0.z,b0.w, b1.x,b1.y,b1.z,b1.w};
        float Cv[8] = {c0.x,c0.y,c0.z,c0.w, c1.x,c1.y,c1.z,c1.w};
        float u = bf2f(sUC[l*136 + d]);
        float dr = Q.x*dw0 + Q.y*dw1 + Q.z*dw2 + Q.w*dw3 + db;
        float te = __expf(dr);
        float dt = (dr > 20.f) ? dr : __logf(1.f + te);
        float dtu = dt * u;
        float yp = 0.f;
        #pragma unroll
        for (int j = 0; j < 8; ++j) {
          float ej = __expf(dt*Av[j]);
          h[j] = h[j]*ej + dtu*Bv[j];
          yp += h[j]*Cv[j];
        }
        float ot = dpp_swap1(yp);
        float ysum = yp + ot;
        if (p == 0) sUC[l*136 + d] = f2bf(ysum + u*dpv);
      }
    }
  }
  __syncthreads();

  // ---- phase 6: yf = y * silu(z) from registers; dir-dependent YF layout. ----
  #pragma unroll
  for (int tt = 0; tt < 2; ++tt) {
    const int st = tt ? st1 : st0;
    size_t rowbase;
    if (dir < 2)       rowbase = ((size_t)n_all*128 + st)*128;
    else if (dir == 2) rowbase = ((size_t)(512 + b*128 + st)*128 + r)*128;
    else               rowbase = ((size_t)(768 + b*128 + (127-st))*128 + r)*128;
    #pragma unroll
    for (int k = 0; k < 8; ++k) {
      const int dz = 16*k + quad*4;
      uint2 yv = *(const uint2*)(sUC + st*136 + dz);
      float y0 = __uint_as_float(yv.x << 16);
      float y1 = __uint_as_float(yv.x & 0xffff0000u);
      float y2 = __uint_as_float(yv.y << 16);
      float y3 = __uint_as_float(yv.y & 0xffff0000u);
      unsigned int z01 = zpk[tt][k][0], z23 = zpk[tt][k][1];
      float z0 = __uint_as_float(z01 << 16);
      float z1 = __uint_as_float(z01 & 0xffff0000u);
      float z2 = __uint_as_float(z23 << 16);
      float z3 = __uint_as_float(z23 & 0xffff0000u);
      uint2 ov;
      ov.x = pk2bf(y0*z0, y1*z1);
      ov.y = pk2bf(y2*z2, y3*z3);
      *(uint2*)(YF + rowbase + dz) = ov;
    }
  }
}

// ---------------------------------------------------------------- K3 (MFMA fuse + LN)
// R23: 32-token tiles. Grid 1024 (b x 128h x 4 w-quarters), 512 thr,
// sYB 33,280B + sLN 1KB -> 4 blk/CU target (launch_bounds(512,8) => VGPR<=64;
// bfr streamed one fragment at a time, each wave computes ONE mt).
__global__ __launch_bounds__(512, 8) void k3_fuse(
    const unsigned short* __restrict__ YF, const unsigned short* __restrict__ MT16,
    const float* __restrict__ fuse_b, const float* __restrict__ ln_g,
    const float* __restrict__ ln_b, float* __restrict__ out)
{
  __shared__ __align__(16) unsigned short sYB[32*520];   // 33,280 B
  __shared__ float sLN[4][32][2];                        //  1,024 B

  const int tid = threadIdx.x;
  const int blk = blockIdx.x;             // 1024
  const int b = blk >> 9;
  const int rem2 = blk & 511;
  const int h = rem2 >> 2;
  const int w0 = (rem2 & 3) * 32;

  // gather: 4 dirg x 32 tok x 128 dd = 16,384 shorts; 4 x uint4 per thread.
  {
    const int tok = tid >> 4;            // 0..31
    const int dd  = (tid & 15) * 8;      // 0..120
    #pragma unroll
    for (int dirg = 0; dirg < 4; ++dirg) {
      int X = (dirg == 1) ? (127 - w0 - tok) : (w0 + tok);
      size_t base = ((size_t)(dirg*256 + b*128 + h)*128 + X)*128 + dd;
      *(uint4*)(sYB + tok*520 + dirg*128 + dd) = *(const uint4*)(YF + base);
    }
  }
  __syncthreads();

  const int wave = tid >> 6;     // 0..7
  const int lane = tid & 63;
  const int m16 = lane & 15;
  const int quad = lane >> 4;
  const int tg   = wave & 1;     // token group (16 tokens)
  const int mq   = wave >> 1;    // mt 0..3 (one per wave -> bfr streamed)
  const int tok  = tg*16 + m16;

  f32x4 acc = {0.f, 0.f, 0.f, 0.f};
  #pragma unroll
  for (int jt = 0; jt < 16; ++jt) {
    short8 bfr = *(const short8*)(sYB + tok*520 + jt*32 + quad*8);
    short8 af  = *(const short8*)(MT16 + (size_t)(mq*16 + m16)*512 + jt*32 + quad*8);
    acc = __builtin_amdgcn_mfma_f32_16x16x32_bf16(af, bfr, acc, 0, 0, 0);
  }

  float fv[4];
  float s1 = 0.f, s2 = 0.f;
  #pragma unroll
  for (int rr = 0; rr < 4; ++rr) {
    int o = mq*16 + quad*4 + rr;
    float v = acc[rr] + fuse_b[o];
    fv[rr] = v;
    s1 += v; s2 += v*v;
  }
  // within-wave: combine quads -> per-token partial over this wave's 16 o
  s1 += __shfl_xor(s1, 16, 64); s1 += __shfl_xor(s1, 32, 64);
  s2 += __shfl_xor(s2, 16, 64); s2 += __shfl_xor(s2, 32, 64);
  if (lane < 16) {
    sLN[mq][tok][0] = s1;
    sLN[mq][tok][1] = s2;
  }
  __syncthreads();
  float t1 = sLN[0][tok][0] + sLN[1][tok][0] + sLN[2][tok][0] + sLN[3][tok][0];
  float t2 = sLN[0][tok][1] + sLN[1][tok][1] + sLN[2][tok][1] + sLN[3][tok][1];
  float mu = t1 * (1.f/64.f);
  float var = t2 * (1.f/64.f) - mu*mu;
  float rs = rsqrtf(var + 1e-5f);

  #pragma unroll
  for (int rr = 0; rr < 4; ++rr) {
    int o = mq*16 + quad*4 + rr;
    float v = (fv[rr] - mu) * rs * ln_g[o] + ln_b[o];
    out[((size_t)(b*64 + o)*128 + h)*128 + (w0 + tok)] = siluf(v);
  }
}

// ---------------------------------------------------------------- host
extern "C" void kernel_launch(void* const* d_in, const int* in_sizes, int n_in,
                              void* d_out, int out_size, void* d_ws, size_t ws_size,
                              hipStream_t stream) {
  const float* x      = (const float*)d_in[0];
  const float* in_w   = (const float*)d_in[1];
  const float* conv_w = (const float*)d_in[2];
  const float* conv_b = (const float*)d_in[3];
  const float* xp_w   = (const float*)d_in[4];
  const float* dtp_w  = (const float*)d_in[5];
  const float* dtp_b  = (const float*)d_in[6];
  const float* A_log  = (const float*)d_in[7];
  const float* Dp     = (const float*)d_in[8];
  const float* out_w  = (const float*)d_in[9];
  const float* fuse_w = (const float*)d_in[10];
  const float* fuse_b = (const float*)d_in[11];
  const float* ln_g   = (const float*)d_in[12];
  const float* ln_b   = (const float*)d_in[13];
  float* out = (float*)d_out;

  // ws layout (BYTES):
  char* ws = (char*)d_ws;
  unsigned short* YF   = (unsigned short*)(ws);              // 33,554,432 (yf, dir-layouts)
  unsigned short* MT16 = (unsigned short*)(ws + 33554432);   //     65,536
  unsigned short* W16  = (unsigned short*)(ws + 33619968);   //    131,072
  unsigned short* XW16 = (unsigned short*)(ws + 33751040);   //     49,152
  unsigned short* XH   = (unsigned short*)(ws + 33800192);   //  4,194,304 (xhwc16)
  unsigned short* XWt  = (unsigned short*)(ws + 37994496);   //  4,194,304 (xwhc16)
  // total 42,188,800 B

  k0_prep<<<dim3(420), dim3(256), 0, stream>>>(out_w, fuse_w, in_w, xp_w, x,
                                               MT16, W16, XW16, XH, XWt);
  k1_front<<<dim3(1024), dim3(256), 0, stream>>>(XH, XWt, W16, XW16, conv_w, conv_b,
                                                 dtp_w, dtp_b, A_log, Dp, YF);
  k3_fuse<<<dim3(1024), dim3(512), 0, stream>>>(YF, MT16, fuse_b, ln_g, ln_b, out);
}